// Round 2
// baseline (481.983 us; speedup 1.0000x reference)
//
#include <hip/hip_runtime.h>
#include <hip/hip_bf16.h>
#include <stdint.h>

#define HEADS 16
#define DHEAD 64
#define DIM   1024
#define SEQ   4096
#define BATCH 4
#define MROWS (BATCH * SEQ)   // 16384
#define NQKV  (3 * DIM)       // 3072

typedef short  s16x8 __attribute__((ext_vector_type(8)));
typedef short  s16x4 __attribute__((ext_vector_type(4)));
typedef float  f32x4 __attribute__((ext_vector_type(4)));
typedef unsigned short u16;

__device__ __forceinline__ u16 f2bf(float f) {
  union { float f; uint32_t u; } v; v.f = f;
  uint32_t r = v.u + 0x7fffu + ((v.u >> 16) & 1u);  // RNE
  return (u16)(r >> 16);
}
__device__ __forceinline__ float bf2f(u16 h) {
  union { uint32_t u; float f; } v; v.u = ((uint32_t)h) << 16;
  return v.f;
}

// async global->LDS, 16B per lane; LDS dest is wave-uniform base + lane*16
__device__ __forceinline__ void gload_lds16(const void* g, void* l) {
  __builtin_amdgcn_global_load_lds((__attribute__((address_space(1))) void*)(g),
                                   (__attribute__((address_space(3))) void*)(l),
                                   16, 0, 0);
}

// ---------------- cast fp32 -> bf16 ----------------
__global__ __launch_bounds__(256) void cast_f32_bf16(const float* __restrict__ src,
                                                     u16* __restrict__ dst, int n) {
  int i = (blockIdx.x * 256 + threadIdx.x) * 4;
  const int stride = gridDim.x * 256 * 4;
  for (; i < n; i += stride) {
    float4 f = *(const float4*)(src + i);
    ushort4 o;
    o.x = f2bf(f.x); o.y = f2bf(f.y); o.z = f2bf(f.z); o.w = f2bf(f.w);
    *(ushort4*)(dst + i) = o;
  }
}

// ---------------- fold W_f into q/k blocks of W_qkv, store transposed bf16 ----------------
// WqkvT[n][k] = sum_d Wqkv[k][reg*1024 + h*64 + d] * Wf[d][j],  n = reg*1024 + h*64 + j
__global__ __launch_bounds__(256) void fold_qk(const float* __restrict__ Wqkv,
                                               const float* __restrict__ Wf,
                                               u16* __restrict__ WqkvT) {
  const int reg = blockIdx.x >> 4;   // 0 = q, 1 = k
  const int h   = blockIdx.x & 15;
  const int base = reg * DIM + h * DHEAD;
  __shared__ float wf[64 * 64];
  __shared__ float wc[64 * 64];
  const int tid = threadIdx.x;
  for (int i = tid; i < 4096; i += 256) wf[i] = Wf[i];
  const int j  = tid & 63;
  const int kq = tid >> 6;
  for (int kc = 0; kc < DIM; kc += 64) {
    __syncthreads();
    for (int i = tid; i < 4096; i += 256) {
      const int r = i >> 6, c = i & 63;
      wc[r * 64 + c] = Wqkv[(size_t)(kc + r) * NQKV + base + c];
    }
    __syncthreads();
    for (int ki = 0; ki < 16; ki++) {
      const int k = kq * 16 + ki;
      float s = 0.f;
#pragma unroll
      for (int d = 0; d < 64; d++) s += wc[k * 64 + d] * wf[d * 64 + j];
      WqkvT[(size_t)(base + j) * DIM + kc + k] = f2bf(s);
    }
  }
}

// ---------------- transpose + cast: dst[n][k] = src[k][colOff + n] ----------------
__global__ __launch_bounds__(256) void transpose_cast(const float* __restrict__ src,
                                                      int srcStride, int colOff,
                                                      u16* __restrict__ dst, int Nt) {
  __shared__ float t[64][65];
  const int ntiles = Nt >> 6;
  const int n0 = (blockIdx.x % ntiles) * 64;
  const int k0 = (blockIdx.x / ntiles) * 64;
  for (int i = threadIdx.x; i < 4096; i += 256) {
    const int r = i >> 6, c = i & 63;
    t[r][c] = src[(size_t)(k0 + r) * srcStride + colOff + n0 + c];
  }
  __syncthreads();
  for (int i = threadIdx.x; i < 4096; i += 256) {
    const int r = i & 63, c = i >> 6;   // consecutive threads -> consecutive k
    dst[(size_t)(n0 + c) * DIM + k0 + r] = f2bf(t[r][c]);
  }
}

// ---------------- main MFMA GEMM: C[M][Nn] = A[M][K] @ Bt[Nn][K]^T ----------------
// EPI 1: bf16 out, cols < 2048 get relu(x + b_f[col%64])      (qkv projection)
// EPI 2: fp32 out, + bias[col]                                 (output projection)
template <int EPI>
__global__ __launch_bounds__(256) void gemm_bt(const u16* __restrict__ A,
                                               const u16* __restrict__ Bt,
                                               void* __restrict__ Cout,
                                               const float* __restrict__ bias,
                                               int M, int Nn, int K) {
  (void)M;
  __shared__ u16 As[128 * 64];
  __shared__ u16 Bs[128 * 64];
  const int tilesN = Nn >> 7;
  const int bm = blockIdx.x / tilesN;
  const int bn = blockIdx.x % tilesN;
  const int m0 = bm << 7, n0 = bn << 7;
  const int tid  = threadIdx.x;
  const int lane = tid & 63;
  const int w    = tid >> 6;
  const int wr = w >> 1, wc = w & 1;
  const int lrow = lane & 15;
  const int lk   = (lane >> 4) << 3;

  f32x4 acc[4][4] = {};

  for (int k0 = 0; k0 < K; k0 += 64) {
    __syncthreads();
#pragma unroll
    for (int i = 0; i < 4; i++) {
      const int s   = i * 256 + tid;
      const int row = s >> 3;
      const int ko  = (s & 7) << 3;
      gload_lds16(A  + (size_t)(m0 + row) * K + k0 + ko,
                  (char*)As + (size_t)(i * 256 + w * 64) * 16);
      gload_lds16(Bt + (size_t)(n0 + row) * K + k0 + ko,
                  (char*)Bs + (size_t)(i * 256 + w * 64) * 16);
    }
    __syncthreads();
#pragma unroll
    for (int kk = 0; kk < 2; kk++) {
      s16x8 af[4], bq[4];
#pragma unroll
      for (int i = 0; i < 4; i++)
        af[i] = *(const s16x8*)&As[(wr * 64 + i * 16 + lrow) * 64 + kk * 32 + lk];
#pragma unroll
      for (int j = 0; j < 4; j++)
        bq[j] = *(const s16x8*)&Bs[(wc * 64 + j * 16 + lrow) * 64 + kk * 32 + lk];
#pragma unroll
      for (int i = 0; i < 4; i++)
#pragma unroll
        for (int j = 0; j < 4; j++)
          acc[i][j] = __builtin_amdgcn_mfma_f32_16x16x32_bf16(af[i], bq[j], acc[i][j], 0, 0, 0);
    }
  }

  const int orow = (lane >> 4) << 2;
#pragma unroll
  for (int i = 0; i < 4; i++) {
#pragma unroll
    for (int j = 0; j < 4; j++) {
      const int col = n0 + wc * 64 + j * 16 + lrow;
#pragma unroll
      for (int t = 0; t < 4; t++) {
        const int row = m0 + wr * 64 + i * 16 + orow + t;
        float v = acc[i][j][t];
        if (EPI == 1) {
          if (col < 2 * DIM) {               // q and k regions: fmap bias + relu
            v += bias[col & 63];
            v = v > 0.f ? v : 0.f;
          }
          ((u16*)Cout)[(size_t)row * Nn + col] = f2bf(v);
        } else {
          ((float*)Cout)[(size_t)row * Nn + col] = v + bias[col];
        }
      }
    }
  }
}

// ---------------- kv partials: per (b,h,chunk-of-512-rows): kv[d][e] += k'[n][d]*v[n][e] ----------------
__global__ __launch_bounds__(256) void kv_ksum(const u16* __restrict__ qkv,
                                               float* __restrict__ kvpart,
                                               float* __restrict__ kspart) {
  const int bh = blockIdx.x >> 3;
  const int chunk = blockIdx.x & 7;
  const int b = bh >> 4, h = bh & 15;
  __shared__ u16 kf[64 * 64];
  __shared__ u16 vf[64 * 64];
  const int tid = threadIdx.x;
  const int d0 = (tid & 15) << 2;
  const int e0 = (tid >> 4) << 2;
  float acc[4][4] = {};
  float ks[4] = {0.f, 0.f, 0.f, 0.f};
  const u16* kbase = qkv + (size_t)(b * SEQ) * NQKV + DIM     + h * DHEAD;
  const u16* vbase = qkv + (size_t)(b * SEQ) * NQKV + 2 * DIM + h * DHEAD;
  for (int r0 = chunk * 512; r0 < chunk * 512 + 512; r0 += 64) {
    __syncthreads();
    for (int s = tid; s < 512; s += 256) {
      const int r = s >> 3, co = (s & 7) << 3;
      *(s16x8*)&kf[r * 64 + co] = *(const s16x8*)(kbase + (size_t)(r0 + r) * NQKV + co);
      *(s16x8*)&vf[r * 64 + co] = *(const s16x8*)(vbase + (size_t)(r0 + r) * NQKV + co);
    }
    __syncthreads();
    for (int n = 0; n < 64; n++) {
      const s16x4 ka = *(const s16x4*)&kf[n * 64 + d0];
      const s16x4 va = *(const s16x4*)&vf[n * 64 + e0];
      float kx[4], vx[4];
#pragma unroll
      for (int i = 0; i < 4; i++) { kx[i] = bf2f((u16)ka[i]); vx[i] = bf2f((u16)va[i]); }
#pragma unroll
      for (int i = 0; i < 4; i++)
#pragma unroll
        for (int j = 0; j < 4; j++) acc[i][j] += kx[i] * vx[j];
      if (e0 == 0) {
#pragma unroll
        for (int i = 0; i < 4; i++) ks[i] += kx[i];
      }
    }
  }
  float* outp = kvpart + (size_t)blockIdx.x * 4096;
#pragma unroll
  for (int i = 0; i < 4; i++)
#pragma unroll
    for (int j = 0; j < 4; j++) outp[(d0 + i) * 64 + e0 + j] = acc[i][j];
  if (tid < 16) {
#pragma unroll
    for (int i = 0; i < 4; i++) kspart[(size_t)blockIdx.x * 64 + d0 + i] = ks[i];
  }
}

// ---------------- deterministic partial reduction ----------------
__global__ __launch_bounds__(256) void reduce_kv(const float* __restrict__ kvpart,
                                                 const float* __restrict__ kspart,
                                                 float* __restrict__ kvbuf,
                                                 float* __restrict__ ksumb) {
  const int idx = blockIdx.x * 256 + threadIdx.x;
  if (idx < 64 * 4096) {
    const int bh = idx >> 12, i = idx & 4095;
    float s = 0.f;
#pragma unroll
    for (int c = 0; c < 8; c++) s += kvpart[(size_t)((bh << 3) + c) * 4096 + i];
    kvbuf[idx] = s;
  } else {
    const int idx2 = idx - 64 * 4096;
    if (idx2 < 4096) {
      const int bh = idx2 >> 6, i = idx2 & 63;
      float s = 0.f;
#pragma unroll
      for (int c = 0; c < 8; c++) s += kspart[((bh << 3) + c) * 64 + i];
      ksumb[idx2] = s;
    }
  }
}

// ---------------- attn out: out[n][e] = (q'[n]·kv[:,e]) / (q'[n]·ksum + 1e-6) ----------------
__global__ __launch_bounds__(256) void attn_out_k(const u16* __restrict__ qkv,
                                                  const float* __restrict__ kvbuf,
                                                  const float* __restrict__ ksumb,
                                                  u16* __restrict__ attn) {
  const int bh = blockIdx.x >> 4;
  const int chunk = blockIdx.x & 15;
  const int b = bh >> 4, h = bh & 15;
  __shared__ float kvs[4096];
  __shared__ float kss[64];
  const int tid = threadIdx.x;
  for (int i = tid; i < 1024; i += 256)
    *(float4*)&kvs[i * 4] = *(const float4*)&kvbuf[(size_t)bh * 4096 + i * 4];
  if (tid < 16)
    *(float4*)&kss[tid * 4] = *(const float4*)&ksumb[bh * 64 + tid * 4];
  __syncthreads();
  const int row = b * SEQ + chunk * 256 + tid;
  const u16* qrow = qkv + (size_t)row * NQKV + h * DHEAD;
  float qv[64];
#pragma unroll
  for (int i = 0; i < 8; i++) {
    const s16x8 qr = *(const s16x8*)(qrow + i * 8);
#pragma unroll
    for (int q = 0; q < 8; q++) qv[i * 8 + q] = bf2f((u16)qr[q]);
  }
  float norm = 1e-6f;
#pragma unroll
  for (int d = 0; d < 64; d++) norm += qv[d] * kss[d];
  const float scale = 1.f / norm;
  u16* orow = attn + (size_t)row * DIM + h * DHEAD;
  for (int e4 = 0; e4 < 16; e4++) {
    float ax = 0.f, ay = 0.f, az = 0.f, aw = 0.f;
#pragma unroll
    for (int d = 0; d < 64; d++) {
      const float4 kq = *(const float4*)&kvs[d * 64 + e4 * 4];
      const float qd = qv[d];
      ax += qd * kq.x; ay += qd * kq.y; az += qd * kq.z; aw += qd * kq.w;
    }
    ushort4 st;
    st.x = f2bf(ax * scale); st.y = f2bf(ay * scale);
    st.z = f2bf(az * scale); st.w = f2bf(aw * scale);
    *(ushort4*)(orow + e4 * 4) = st;
  }
}

extern "C" void kernel_launch(void* const* d_in, const int* in_sizes, int n_in,
                              void* d_out, int out_size, void* d_ws, size_t ws_size,
                              hipStream_t stream) {
  (void)in_sizes; (void)n_in; (void)out_size; (void)ws_size;
  const float* x     = (const float*)d_in[0];
  const float* Wqkv  = (const float*)d_in[1];
  const float* Wf    = (const float*)d_in[2];
  const float* bfv   = (const float*)d_in[3];
  const float* Wout  = (const float*)d_in[4];
  const float* bout  = (const float*)d_in[5];
  float* out = (float*)d_out;
  char* ws = (char*)d_ws;

  u16*   wqkvT = (u16*)(ws + 0);              // 3072*1024 bf16   = 6,291,456 B
  u16*   woutT = (u16*)(ws + 6291456);        // 1024*1024 bf16   = 2,097,152 B
  u16*   xb    = (u16*)(ws + 8388608);        // 16384*1024 bf16  = 33,554,432 B
  u16*   qkvb  = (u16*)(ws + 41943040);       // 16384*3072 bf16  = 100,663,296 B
  u16*   attn  = (u16*)(ws + 142606336);      // 16384*1024 bf16  = 33,554,432 B
  float* kvp   = (float*)(ws + 176160768);    // 512*4096 f32     = 8,388,608 B
  float* ksp   = (float*)(ws + 184549376);    // 512*64 f32       = 131,072 B
  float* kvbuf = (float*)(ws + 184680448);    // 64*4096 f32      = 1,048,576 B
  float* ksumb = (float*)(ws + 185729024);    // 64*64 f32        = 16,384 B
  // total ws usage: 185,745,408 B

  cast_f32_bf16<<<2048, 256, 0, stream>>>(x, xb, MROWS * DIM);
  fold_qk<<<32, 256, 0, stream>>>(Wqkv, Wf, wqkvT);
  transpose_cast<<<256, 256, 0, stream>>>(Wqkv, NQKV, 2 * DIM, wqkvT + (size_t)2 * DIM * DIM, DIM);
  transpose_cast<<<256, 256, 0, stream>>>(Wout, DIM, 0, woutT, DIM);
  gemm_bt<1><<<(MROWS / 128) * (NQKV / 128), 256, 0, stream>>>(xb, wqkvT, qkvb, bfv,
                                                               MROWS, NQKV, DIM);
  kv_ksum<<<64 * 8, 256, 0, stream>>>(qkvb, kvp, ksp);
  reduce_kv<<<(64 * 4096 + 64 * 64 + 255) / 256, 256, 0, stream>>>(kvp, ksp, kvbuf, ksumb);
  attn_out_k<<<64 * 16, 256, 0, stream>>>(qkvb, kvbuf, ksumb, attn);
  gemm_bt<2><<<(MROWS / 128) * (DIM / 128), 256, 0, stream>>>(attn, woutT, out, bout,
                                                              MROWS, DIM, DIM);
}

// Round 3
// 429.459 us; speedup vs baseline: 1.1223x; 1.1223x over previous
//
#include <hip/hip_runtime.h>
#include <hip/hip_bf16.h>
#include <stdint.h>

#define HEADS 16
#define DHEAD 64
#define DIM   1024
#define SEQ   4096
#define BATCH 4
#define MROWS (BATCH * SEQ)   // 16384
#define NQKV  (3 * DIM)       // 3072

typedef short  s16x8 __attribute__((ext_vector_type(8)));
typedef short  s16x4 __attribute__((ext_vector_type(4)));
typedef float  f32x4 __attribute__((ext_vector_type(4)));
typedef unsigned short u16;

__device__ __forceinline__ u16 f2bf(float f) {
  union { float f; uint32_t u; } v; v.f = f;
  uint32_t r = v.u + 0x7fffu + ((v.u >> 16) & 1u);  // RNE
  return (u16)(r >> 16);
}
__device__ __forceinline__ float bf2f(u16 h) {
  union { uint32_t u; float f; } v; v.u = ((uint32_t)h) << 16;
  return v.f;
}

// async global->LDS, 16B per lane; LDS dest is wave-uniform base + lane*16
__device__ __forceinline__ void gload_lds16(const void* g, void* l) {
  __builtin_amdgcn_global_load_lds((__attribute__((address_space(1))) void*)(g),
                                   (__attribute__((address_space(3))) void*)(l),
                                   16, 0, 0);
}

// ---------------- cast fp32 -> bf16 ----------------
__global__ __launch_bounds__(256) void cast_f32_bf16(const float* __restrict__ src,
                                                     u16* __restrict__ dst, int n) {
  int i = (blockIdx.x * 256 + threadIdx.x) * 4;
  const int stride = gridDim.x * 256 * 4;
  for (; i < n; i += stride) {
    float4 f = *(const float4*)(src + i);
    ushort4 o;
    o.x = f2bf(f.x); o.y = f2bf(f.y); o.z = f2bf(f.z); o.w = f2bf(f.w);
    *(ushort4*)(dst + i) = o;
  }
}

// ---------------- fold W_f into q/k blocks of W_qkv, store transposed bf16 ----------------
// WqkvT[n][k] = sum_d Wqkv[k][reg*1024 + h*64 + d] * Wf[d][j],  n = reg*1024 + h*64 + j
__global__ __launch_bounds__(256) void fold_qk(const float* __restrict__ Wqkv,
                                               const float* __restrict__ Wf,
                                               u16* __restrict__ WqkvT) {
  const int reg = blockIdx.x >> 4;   // 0 = q, 1 = k
  const int h   = blockIdx.x & 15;
  const int base = reg * DIM + h * DHEAD;
  __shared__ float wf[64 * 64];
  __shared__ float wc[64 * 64];
  const int tid = threadIdx.x;
  for (int i = tid; i < 4096; i += 256) wf[i] = Wf[i];
  const int j  = tid & 63;
  const int kq = tid >> 6;
  for (int kc = 0; kc < DIM; kc += 64) {
    __syncthreads();
    for (int i = tid; i < 4096; i += 256) {
      const int r = i >> 6, c = i & 63;
      wc[r * 64 + c] = Wqkv[(size_t)(kc + r) * NQKV + base + c];
    }
    __syncthreads();
    for (int ki = 0; ki < 16; ki++) {
      const int k = kq * 16 + ki;
      float s = 0.f;
#pragma unroll
      for (int d = 0; d < 64; d++) s += wc[k * 64 + d] * wf[d * 64 + j];
      WqkvT[(size_t)(base + j) * DIM + kc + k] = f2bf(s);
    }
  }
}

// ---------------- transpose + cast: dst[n][k] = src[k][colOff + n] ----------------
__global__ __launch_bounds__(256) void transpose_cast(const float* __restrict__ src,
                                                      int srcStride, int colOff,
                                                      u16* __restrict__ dst, int Nt) {
  __shared__ float t[64][65];
  const int ntiles = Nt >> 6;
  const int n0 = (blockIdx.x % ntiles) * 64;
  const int k0 = (blockIdx.x / ntiles) * 64;
  for (int i = threadIdx.x; i < 4096; i += 256) {
    const int r = i >> 6, c = i & 63;
    t[r][c] = src[(size_t)(k0 + r) * srcStride + colOff + n0 + c];
  }
  __syncthreads();
  for (int i = threadIdx.x; i < 4096; i += 256) {
    const int r = i & 63, c = i >> 6;   // consecutive threads -> consecutive k
    dst[(size_t)(n0 + c) * DIM + k0 + r] = f2bf(t[r][c]);
  }
}

// ---------------- main MFMA GEMM: C[M][Nn] = A[M][K] @ Bt[Nn][K]^T ----------------
// 2-phase double-buffered pipeline, T2 XOR-swizzled LDS (pre-swizzled global src,
// linear global_load_lds dest, swizzled ds_read), swapped-operand MFMA so each
// lane holds 4 consecutive C columns (vectorized epilogue), T1 XCD chunking.
// EPI 1: bf16 out, cols < 2048 get relu(x + b_f[col%64])      (qkv projection)
// EPI 2: fp32 out, + bias[col]                                 (output projection)
template <int EPI>
__global__ __launch_bounds__(256) void gemm_bt(const u16* __restrict__ A,
                                               const u16* __restrict__ Bt,
                                               void* __restrict__ Cout,
                                               const float* __restrict__ bias,
                                               int M, int Nn, int K) {
  (void)M;
  __shared__ u16 smem[2][2][128 * 64];   // [buf][A/B][row*64 + slot*8] — 64 KiB
  const int tilesN = Nn >> 7;
  // T1: bijective XCD chunking (gridDim.x % 8 == 0 for both call sites)
  const int nwg  = gridDim.x;
  const int bid  = (blockIdx.x & 7) * (nwg >> 3) + (blockIdx.x >> 3);
  const int bm = bid / tilesN;
  const int bn = bid % tilesN;
  const int m0 = bm << 7, n0 = bn << 7;
  const int tid  = threadIdx.x;
  const int lane = tid & 63;
  const int w    = tid >> 6;
  const int wr = w >> 1, wc = w & 1;
  const int lrow = lane & 15;
  const int hi   = lane >> 4;

  // staging address (pre-swizzled global source): lane handles (row, physslot)
  const int srow  = tid >> 3;          // per chunk i: row = i*32 + srow
  const int pslot = tid & 7;
  const int gk    = (pslot ^ (srow & 7)) << 3;   // global k element offset
  const u16* aSrc = A  + (size_t)(m0 + srow) * K + gk;
  const u16* bSrc = Bt + (size_t)(n0 + srow) * K + gk;
  const int ldsOff = (w * 64) * 16;    // wave-uniform part of dest (byte)

  f32x4 acc[4][4] = {};
  const int NT = K >> 6;

#define STAGE(buf, kt)                                                          \
  {                                                                             \
    _Pragma("unroll")                                                           \
    for (int i_ = 0; i_ < 4; i_++) {                                            \
      gload_lds16(aSrc + (size_t)(i_ * 32) * K + (kt) * 64,                     \
                  (char*)&smem[buf][0][0] + i_ * 4096 + ldsOff);                \
      gload_lds16(bSrc + (size_t)(i_ * 32) * K + (kt) * 64,                     \
                  (char*)&smem[buf][1][0] + i_ * 4096 + ldsOff);                \
    }                                                                           \
  }

  STAGE(0, 0);
  __syncthreads();                      // vmcnt(0) drain + barrier
  int cur = 0;

  for (int t = 0; t < NT; t++) {
    if (t + 1 < NT) STAGE(cur ^ 1, t + 1);   // issue next tile early
    // swizzled ds_read: row r, k-slot s  ->  byte r*128 + (s ^ (r&7))*16
#pragma unroll
    for (int kk = 0; kk < 2; kk++) {
      s16x8 af[4], bq[4];
#pragma unroll
      for (int i = 0; i < 4; i++) {
        const int row = wr * 64 + i * 16 + lrow;
        const int sl  = (kk * 4 + hi) ^ (lrow & 7);
        af[i] = *(const s16x8*)&smem[cur][0][row * 64 + sl * 8];
      }
#pragma unroll
      for (int j = 0; j < 4; j++) {
        const int row = wc * 64 + j * 16 + lrow;
        const int sl  = (kk * 4 + hi) ^ (lrow & 7);
        bq[j] = *(const s16x8*)&smem[cur][1][row * 64 + sl * 8];
      }
#pragma unroll
      for (int i = 0; i < 4; i++)
#pragma unroll
        for (int j = 0; j < 4; j++)
          acc[i][j] = __builtin_amdgcn_mfma_f32_16x16x32_bf16(bq[j], af[i], acc[i][j], 0, 0, 0);
    }
    __syncthreads();                    // drains stage vmcnt after compute
    cur ^= 1;
  }
#undef STAGE

  // Swapped-operand D layout: lane&15 -> C row (m), reg t -> C col (n)
  const int m  = m0 + wr * 64 + lrow;
  const int nb0 = n0 + wc * 64 + (hi << 2);
#pragma unroll
  for (int i = 0; i < 4; i++) {
    const int row = m + i * 16;
#pragma unroll
    for (int j = 0; j < 4; j++) {
      const int nb = nb0 + j * 16;
      float v0 = acc[i][j][0], v1 = acc[i][j][1], v2 = acc[i][j][2], v3 = acc[i][j][3];
      if (EPI == 1) {
        if (nb < 2 * DIM) {             // q and k regions: fmap bias + relu
          const int bb = nb & 63;
          v0 += bias[bb];     v1 += bias[bb + 1];
          v2 += bias[bb + 2]; v3 += bias[bb + 3];
          v0 = v0 > 0.f ? v0 : 0.f;  v1 = v1 > 0.f ? v1 : 0.f;
          v2 = v2 > 0.f ? v2 : 0.f;  v3 = v3 > 0.f ? v3 : 0.f;
        }
        uint2 st;
        st.x = (uint32_t)f2bf(v0) | ((uint32_t)f2bf(v1) << 16);
        st.y = (uint32_t)f2bf(v2) | ((uint32_t)f2bf(v3) << 16);
        *(uint2*)((u16*)Cout + (size_t)row * Nn + nb) = st;
      } else {
        float4 st;
        st.x = v0 + bias[nb];     st.y = v1 + bias[nb + 1];
        st.z = v2 + bias[nb + 2]; st.w = v3 + bias[nb + 3];
        *(float4*)((float*)Cout + (size_t)row * Nn + nb) = st;
      }
    }
  }
}

// ---------------- kv partials: per (b,h,chunk-of-512-rows): kv[d][e] += k'[n][d]*v[n][e] ----------------
__global__ __launch_bounds__(256) void kv_ksum(const u16* __restrict__ qkv,
                                               float* __restrict__ kvpart,
                                               float* __restrict__ kspart) {
  const int bh = blockIdx.x >> 3;
  const int chunk = blockIdx.x & 7;
  const int b = bh >> 4, h = bh & 15;
  __shared__ u16 kf[64 * 64];
  __shared__ u16 vf[64 * 64];
  const int tid = threadIdx.x;
  const int d0 = (tid & 15) << 2;
  const int e0 = (tid >> 4) << 2;
  float acc[4][4] = {};
  float ks[4] = {0.f, 0.f, 0.f, 0.f};
  const u16* kbase = qkv + (size_t)(b * SEQ) * NQKV + DIM     + h * DHEAD;
  const u16* vbase = qkv + (size_t)(b * SEQ) * NQKV + 2 * DIM + h * DHEAD;
  for (int r0 = chunk * 512; r0 < chunk * 512 + 512; r0 += 64) {
    __syncthreads();
    for (int s = tid; s < 512; s += 256) {
      const int r = s >> 3, co = (s & 7) << 3;
      *(s16x8*)&kf[r * 64 + co] = *(const s16x8*)(kbase + (size_t)(r0 + r) * NQKV + co);
      *(s16x8*)&vf[r * 64 + co] = *(const s16x8*)(vbase + (size_t)(r0 + r) * NQKV + co);
    }
    __syncthreads();
    for (int n = 0; n < 64; n++) {
      const s16x4 ka = *(const s16x4*)&kf[n * 64 + d0];
      const s16x4 va = *(const s16x4*)&vf[n * 64 + e0];
      float kx[4], vx[4];
#pragma unroll
      for (int i = 0; i < 4; i++) { kx[i] = bf2f((u16)ka[i]); vx[i] = bf2f((u16)va[i]); }
#pragma unroll
      for (int i = 0; i < 4; i++)
#pragma unroll
        for (int j = 0; j < 4; j++) acc[i][j] += kx[i] * vx[j];
      if (e0 == 0) {
#pragma unroll
        for (int i = 0; i < 4; i++) ks[i] += kx[i];
      }
    }
  }
  float* outp = kvpart + (size_t)blockIdx.x * 4096;
#pragma unroll
  for (int i = 0; i < 4; i++)
#pragma unroll
    for (int j = 0; j < 4; j++) outp[(d0 + i) * 64 + e0 + j] = acc[i][j];
  if (tid < 16) {
#pragma unroll
    for (int i = 0; i < 4; i++) kspart[(size_t)blockIdx.x * 64 + d0 + i] = ks[i];
  }
}

// ---------------- deterministic partial reduction ----------------
__global__ __launch_bounds__(256) void reduce_kv(const float* __restrict__ kvpart,
                                                 const float* __restrict__ kspart,
                                                 float* __restrict__ kvbuf,
                                                 float* __restrict__ ksumb) {
  const int idx = blockIdx.x * 256 + threadIdx.x;
  if (idx < 64 * 4096) {
    const int bh = idx >> 12, i = idx & 4095;
    float s = 0.f;
#pragma unroll
    for (int c = 0; c < 8; c++) s += kvpart[(size_t)((bh << 3) + c) * 4096 + i];
    kvbuf[idx] = s;
  } else {
    const int idx2 = idx - 64 * 4096;
    if (idx2 < 4096) {
      const int bh = idx2 >> 6, i = idx2 & 63;
      float s = 0.f;
#pragma unroll
      for (int c = 0; c < 8; c++) s += kspart[((bh << 3) + c) * 64 + i];
      ksumb[idx2] = s;
    }
  }
}

// ---------------- attn out: out[n][e] = (q'[n]·kv[:,e]) / (q'[n]·ksum + 1e-6) ----------------
__global__ __launch_bounds__(256) void attn_out_k(const u16* __restrict__ qkv,
                                                  const float* __restrict__ kvbuf,
                                                  const float* __restrict__ ksumb,
                                                  u16* __restrict__ attn) {
  const int bh = blockIdx.x >> 4;
  const int chunk = blockIdx.x & 15;
  const int b = bh >> 4, h = bh & 15;
  __shared__ float kvs[4096];
  __shared__ float kss[64];
  const int tid = threadIdx.x;
  for (int i = tid; i < 1024; i += 256)
    *(float4*)&kvs[i * 4] = *(const float4*)&kvbuf[(size_t)bh * 4096 + i * 4];
  if (tid < 16)
    *(float4*)&kss[tid * 4] = *(const float4*)&ksumb[bh * 64 + tid * 4];
  __syncthreads();
  const int row = b * SEQ + chunk * 256 + tid;
  const u16* qrow = qkv + (size_t)row * NQKV + h * DHEAD;
  float qv[64];
#pragma unroll
  for (int i = 0; i < 8; i++) {
    const s16x8 qr = *(const s16x8*)(qrow + i * 8);
#pragma unroll
    for (int q = 0; q < 8; q++) qv[i * 8 + q] = bf2f((u16)qr[q]);
  }
  float norm = 1e-6f;
#pragma unroll
  for (int d = 0; d < 64; d++) norm += qv[d] * kss[d];
  const float scale = 1.f / norm;
  u16* orow = attn + (size_t)row * DIM + h * DHEAD;
  for (int e4 = 0; e4 < 16; e4++) {
    float ax = 0.f, ay = 0.f, az = 0.f, aw = 0.f;
#pragma unroll
    for (int d = 0; d < 64; d++) {
      const float4 kq = *(const float4*)&kvs[d * 64 + e4 * 4];
      const float qd = qv[d];
      ax += qd * kq.x; ay += qd * kq.y; az += qd * kq.z; aw += qd * kq.w;
    }
    ushort4 st;
    st.x = f2bf(ax * scale); st.y = f2bf(ay * scale);
    st.z = f2bf(az * scale); st.w = f2bf(aw * scale);
    *(ushort4*)(orow + e4 * 4) = st;
  }
}

extern "C" void kernel_launch(void* const* d_in, const int* in_sizes, int n_in,
                              void* d_out, int out_size, void* d_ws, size_t ws_size,
                              hipStream_t stream) {
  (void)in_sizes; (void)n_in; (void)out_size; (void)ws_size;
  const float* x     = (const float*)d_in[0];
  const float* Wqkv  = (const float*)d_in[1];
  const float* Wf    = (const float*)d_in[2];
  const float* bfv   = (const float*)d_in[3];
  const float* Wout  = (const float*)d_in[4];
  const float* bout  = (const float*)d_in[5];
  float* out = (float*)d_out;
  char* ws = (char*)d_ws;

  u16*   wqkvT = (u16*)(ws + 0);              // 3072*1024 bf16   = 6,291,456 B
  u16*   woutT = (u16*)(ws + 6291456);        // 1024*1024 bf16   = 2,097,152 B
  u16*   xb    = (u16*)(ws + 8388608);        // 16384*1024 bf16  = 33,554,432 B
  u16*   qkvb  = (u16*)(ws + 41943040);       // 16384*3072 bf16  = 100,663,296 B
  u16*   attn  = (u16*)(ws + 142606336);      // 16384*1024 bf16  = 33,554,432 B
  float* kvp   = (float*)(ws + 176160768);    // 512*4096 f32     = 8,388,608 B
  float* ksp   = (float*)(ws + 184549376);    // 512*64 f32       = 131,072 B
  float* kvbuf = (float*)(ws + 184680448);    // 64*4096 f32      = 1,048,576 B
  float* ksumb = (float*)(ws + 185729024);    // 64*64 f32        = 16,384 B
  // total ws usage: 185,745,408 B

  cast_f32_bf16<<<2048, 256, 0, stream>>>(x, xb, MROWS * DIM);
  fold_qk<<<32, 256, 0, stream>>>(Wqkv, Wf, wqkvT);
  transpose_cast<<<256, 256, 0, stream>>>(Wqkv, NQKV, 2 * DIM, wqkvT + (size_t)2 * DIM * DIM, DIM);
  transpose_cast<<<256, 256, 0, stream>>>(Wout, DIM, 0, woutT, DIM);
  gemm_bt<1><<<(MROWS / 128) * (NQKV / 128), 256, 0, stream>>>(xb, wqkvT, qkvb, bfv,
                                                               MROWS, NQKV, DIM);
  kv_ksum<<<64 * 8, 256, 0, stream>>>(qkvb, kvp, ksp);
  reduce_kv<<<(64 * 4096 + 64 * 64 + 255) / 256, 256, 0, stream>>>(kvp, ksp, kvbuf, ksumb);
  attn_out_k<<<64 * 16, 256, 0, stream>>>(qkvb, kvbuf, ksumb, attn);
  gemm_bt<2><<<(MROWS / 128) * (DIM / 128), 256, 0, stream>>>(attn, woutT, out, bout,
                                                              MROWS, DIM, DIM);
}

// Round 4
// 395.303 us; speedup vs baseline: 1.2193x; 1.0864x over previous
//
#include <hip/hip_runtime.h>
#include <hip/hip_bf16.h>
#include <stdint.h>

#define HEADS 16
#define DHEAD 64
#define DIM   1024
#define SEQ   4096
#define BATCH 4
#define MROWS (BATCH * SEQ)   // 16384
#define NQKV  (3 * DIM)       // 3072

typedef short  s16x8 __attribute__((ext_vector_type(8)));
typedef short  s16x4 __attribute__((ext_vector_type(4)));
typedef float  f32x4 __attribute__((ext_vector_type(4)));
typedef unsigned short u16;

__device__ __forceinline__ u16 f2bf(float f) {
  union { float f; uint32_t u; } v; v.f = f;
  uint32_t r = v.u + 0x7fffu + ((v.u >> 16) & 1u);  // RNE
  return (u16)(r >> 16);
}
__device__ __forceinline__ float bf2f(u16 h) {
  union { uint32_t u; float f; } v; v.u = ((uint32_t)h) << 16;
  return v.f;
}

// async global->LDS, 16B per lane; LDS dest is wave-uniform base + lane*16
__device__ __forceinline__ void gload_lds16(const void* g, void* l) {
  __builtin_amdgcn_global_load_lds((__attribute__((address_space(1))) void*)(g),
                                   (__attribute__((address_space(3))) void*)(l),
                                   16, 0, 0);
}

// ---------------- cast fp32 -> bf16 ----------------
__global__ __launch_bounds__(256) void cast_f32_bf16(const float* __restrict__ src,
                                                     u16* __restrict__ dst, int n) {
  int i = (blockIdx.x * 256 + threadIdx.x) * 4;
  const int stride = gridDim.x * 256 * 4;
  for (; i < n; i += stride) {
    float4 f = *(const float4*)(src + i);
    ushort4 o;
    o.x = f2bf(f.x); o.y = f2bf(f.y); o.z = f2bf(f.z); o.w = f2bf(f.w);
    *(ushort4*)(dst + i) = o;
  }
}

// ---------------- fold W_f into q/k blocks of W_qkv, store transposed bf16 ----------------
__global__ __launch_bounds__(256) void fold_qk(const float* __restrict__ Wqkv,
                                               const float* __restrict__ Wf,
                                               u16* __restrict__ WqkvT) {
  const int reg = blockIdx.x >> 4;   // 0 = q, 1 = k
  const int h   = blockIdx.x & 15;
  const int base = reg * DIM + h * DHEAD;
  __shared__ float wf[64 * 64];
  __shared__ float wc[64 * 64];
  const int tid = threadIdx.x;
  for (int i = tid; i < 4096; i += 256) wf[i] = Wf[i];
  const int j  = tid & 63;
  const int kq = tid >> 6;
  for (int kc = 0; kc < DIM; kc += 64) {
    __syncthreads();
    for (int i = tid; i < 4096; i += 256) {
      const int r = i >> 6, c = i & 63;
      wc[r * 64 + c] = Wqkv[(size_t)(kc + r) * NQKV + base + c];
    }
    __syncthreads();
    for (int ki = 0; ki < 16; ki++) {
      const int k = kq * 16 + ki;
      float s = 0.f;
#pragma unroll
      for (int d = 0; d < 64; d++) s += wc[k * 64 + d] * wf[d * 64 + j];
      WqkvT[(size_t)(base + j) * DIM + kc + k] = f2bf(s);
    }
  }
}

// ---------------- transpose + cast: dst[n][k] = src[k][colOff + n] ----------------
__global__ __launch_bounds__(256) void transpose_cast(const float* __restrict__ src,
                                                      int srcStride, int colOff,
                                                      u16* __restrict__ dst, int Nt) {
  __shared__ float t[64][65];
  const int ntiles = Nt >> 6;
  const int n0 = (blockIdx.x % ntiles) * 64;
  const int k0 = (blockIdx.x / ntiles) * 64;
  for (int i = threadIdx.x; i < 4096; i += 256) {
    const int r = i >> 6, c = i & 63;
    t[r][c] = src[(size_t)(k0 + r) * srcStride + colOff + n0 + c];
  }
  __syncthreads();
  for (int i = threadIdx.x; i < 4096; i += 256) {
    const int r = i & 63, c = i >> 6;
    dst[(size_t)(n0 + c) * DIM + k0 + r] = f2bf(t[r][c]);
  }
}

// ---------------- 256x256 8-phase MFMA GEMM: C[M][Nn] = A[M][K] @ Bt[Nn][K]^T ----------------
// 8 waves (2M x 4N), BK=64, 2 K-tiles/iter, dbuf LDS 128 KiB, T2 XOR swizzle
// (pre-swizzled global source + swizzled ds_read), counted vmcnt(6) at P4/P8,
// raw s_barrier, setprio around MFMA clusters, T1 XCD chunk + 4-row grouping.
// EPI 1: bf16 out, cols < 2048 get relu(x + b_f[col%64]);  EPI 2: fp32 out + bias.
template <int EPI>
__global__ __launch_bounds__(512, 2) void gemm8p(const u16* __restrict__ A,
                                                 const u16* __restrict__ Bt,
                                                 void* __restrict__ Cout,
                                                 const float* __restrict__ bias,
                                                 int Nn, int K) {
  __shared__ __align__(16) u16 smem[2][2][2][128 * 64];  // [buf][A0/B1][half] = 128 KiB
  const int tilesN = Nn >> 8;
  const int cpx   = gridDim.x >> 3;          // blocks per XCD (grid % 8 == 0)
  const int xcd   = blockIdx.x & 7;
  const int local = blockIdx.x >> 3;
  const int bmPerX = cpx / tilesN;           // 8 for both call sites
  const int perG = 4 * tilesN;               // 4-bm group for L2 locality
  const int g = local / perG, rrm = local % perG;
  const int bm = xcd * bmPerX + g * 4 + rrm / tilesN;
  const int bn = rrm % tilesN;
  const int m0 = bm << 8, n0 = bn << 8;

  const int tid  = threadIdx.x;
  const int lane = tid & 63;
  const int w    = tid >> 6;
  const int wr = w >> 2, wcn = w & 3;
  const int lrow = lane & 15;
  const int hi   = lane >> 4;
  const int sx   = lrow & 7;

  // staging: 512 thr x 2 loads cover one 128x64 half (1024 x 16B); pre-swizzled src
  const int srow  = tid >> 3;                // 0..63 (load1 adds 64; same &7)
  const int pslot = tid & 7;
  const int gk    = (pslot ^ (srow & 7)) << 3;
  const u16* aBase = A  + (size_t)m0 * K + gk;
  const u16* bBase = Bt + (size_t)n0 * K + gk;

#define STG(buf, op, half, kt, gb)                                             \
  { const u16* s0_ = (gb) + (size_t)((half) * 128 + srow) * K + (kt) * 64;     \
    char* d0_ = (char*)&smem[buf][op][half][0] + tid * 16;                     \
    gload_lds16(s0_, d0_);                                                     \
    gload_lds16(s0_ + (size_t)64 * K, d0_ + 8192); }

#define RDA(buf, dst, mbase)                                                   \
  _Pragma("unroll") for (int mi_ = 0; mi_ < 4; mi_++)                          \
  _Pragma("unroll") for (int kk_ = 0; kk_ < 2; kk_++) {                        \
    const int r_ = ((mbase) + mi_) * 16 + lrow;                                \
    dst[mi_][kk_] = *(const s16x8*)&smem[buf][0][wr]                           \
                        [r_ * 64 + ((kk_ * 4 + hi) ^ sx) * 8]; }

#define RDB(buf, dst, nbase)                                                   \
  _Pragma("unroll") for (int nj_ = 0; nj_ < 2; nj_++)                          \
  _Pragma("unroll") for (int kk_ = 0; kk_ < 2; kk_++) {                        \
    const int r_ = (wcn & 1) * 64 + ((nbase) + nj_) * 16 + lrow;               \
    dst[nj_][kk_] = *(const s16x8*)&smem[buf][1][wcn >> 1]                     \
                        [r_ * 64 + ((kk_ * 4 + hi) ^ sx) * 8]; }

#define MM(mbase, nbase, areg, breg)                                           \
  _Pragma("unroll") for (int mi_ = 0; mi_ < 4; mi_++)                          \
  _Pragma("unroll") for (int nj_ = 0; nj_ < 2; nj_++)                          \
  _Pragma("unroll") for (int kk_ = 0; kk_ < 2; kk_++)                          \
    acc[(mbase) + mi_][(nbase) + nj_] = __builtin_amdgcn_mfma_f32_16x16x32_bf16( \
        breg[nj_][kk_], areg[mi_][kk_], acc[(mbase) + mi_][(nbase) + nj_], 0, 0, 0);

#define WLG  asm volatile("s_waitcnt lgkmcnt(0)" ::: "memory")
#define WVM6 asm volatile("s_waitcnt vmcnt(6)" ::: "memory")
#define WVM0 asm volatile("s_waitcnt vmcnt(0)" ::: "memory")
#define BAR  __builtin_amdgcn_s_barrier()
#define PRIO1 __builtin_amdgcn_s_setprio(1)
#define PRIO0 __builtin_amdgcn_s_setprio(0)

  f32x4 acc[8][4] = {};
  const int NT  = K >> 6;      // K-tiles (even)
  const int NIT = NT >> 1;     // iterations (2 tiles each)

  // prologue: buf0 <- tile0, buf1 <- tile1; drain buf0 (+2), keep 6 in flight
  STG(0, 0, 0, 0, aBase); STG(0, 0, 1, 0, aBase);
  STG(0, 1, 0, 0, bBase); STG(0, 1, 1, 0, bBase);
  STG(1, 0, 0, 1, aBase); STG(1, 0, 1, 1, aBase);
  STG(1, 1, 0, 1, bBase); STG(1, 1, 1, 1, bBase);
  WVM6; BAR;

  for (int it = 0; it < NIT; ++it) {
    const int tE = 2 * it + 2, tO = 2 * it + 3;
    const bool pf = (tE < NT);
    s16x8 a[4][2], bl[2][2], bh[2][2];
    // P1: Q(mlo,nlo) of even tile
    RDA(0, a, 0); RDB(0, bl, 0);
    BAR; WLG;
    PRIO1; MM(0, 0, a, bl); PRIO0;
    BAR;
    // P2: Q(mlo,nhi)
    RDB(0, bh, 2);
    BAR; WLG;
    PRIO1; MM(0, 2, a, bh); PRIO0;
    BAR;
    // P3: Q(mhi,nhi)    | stage b0.B-lo (tile tE)
    RDA(0, a, 4);
    if (pf) STG(0, 1, 0, tE, bBase);
    BAR; WLG;
    PRIO1; MM(4, 2, a, bh); PRIO0;
    BAR;
    // P4: Q(mhi,nlo)    | stage b0.B-hi + b0.A-lo; counted vmcnt
    if (pf) { STG(0, 1, 1, tE, bBase); STG(0, 0, 0, tE, aBase); }
    BAR;
    if (pf) { WVM6; } else { WVM0; }
    PRIO1; MM(4, 0, a, bl); PRIO0;
    BAR;
    // P5: Q(mlo,nlo) of odd tile | stage b0.A-hi
    RDA(1, a, 0); RDB(1, bl, 0);
    if (pf) STG(0, 0, 1, tE, aBase);
    BAR; WLG;
    PRIO1; MM(0, 0, a, bl); PRIO0;
    BAR;
    // P6: Q(mlo,nhi)
    RDB(1, bh, 2);
    BAR; WLG;
    PRIO1; MM(0, 2, a, bh); PRIO0;
    BAR;
    // P7: Q(mhi,nhi)    | stage b1.B-lo + b1.B-hi (tile tO)
    RDA(1, a, 4);
    if (pf) { STG(1, 1, 0, tO, bBase); STG(1, 1, 1, tO, bBase); }
    BAR; WLG;
    PRIO1; MM(4, 2, a, bh); PRIO0;
    BAR;
    // P8: Q(mhi,nlo)    | stage b1.A-lo + b1.A-hi; counted vmcnt
    if (pf) { STG(1, 0, 0, tO, aBase); STG(1, 0, 1, tO, aBase); }
    BAR;
    if (pf) { WVM6; } else { WVM0; }
    PRIO1; MM(4, 0, a, bl); PRIO0;
    BAR;
  }

  // epilogue: swapped-operand D layout — lane&15 -> M row, regs -> 4 consecutive N cols
  const int mrow = m0 + wr * 128 + lrow;
  const int nb0  = n0 + wcn * 64 + (hi << 2);
#pragma unroll
  for (int mi = 0; mi < 8; mi++) {
    const int row = mrow + mi * 16;
#pragma unroll
    for (int nj = 0; nj < 4; nj++) {
      const int nb = nb0 + nj * 16;
      float v0 = acc[mi][nj][0], v1 = acc[mi][nj][1];
      float v2 = acc[mi][nj][2], v3 = acc[mi][nj][3];
      if (EPI == 1) {
        if (nb < 2 * DIM) {
          const int bb = nb & 63;
          v0 += bias[bb];     v1 += bias[bb + 1];
          v2 += bias[bb + 2]; v3 += bias[bb + 3];
          v0 = v0 > 0.f ? v0 : 0.f;  v1 = v1 > 0.f ? v1 : 0.f;
          v2 = v2 > 0.f ? v2 : 0.f;  v3 = v3 > 0.f ? v3 : 0.f;
        }
        uint2 st;
        st.x = (uint32_t)f2bf(v0) | ((uint32_t)f2bf(v1) << 16);
        st.y = (uint32_t)f2bf(v2) | ((uint32_t)f2bf(v3) << 16);
        *(uint2*)((u16*)Cout + (size_t)row * Nn + nb) = st;
      } else {
        float4 st;
        st.x = v0 + bias[nb];     st.y = v1 + bias[nb + 1];
        st.z = v2 + bias[nb + 2]; st.w = v3 + bias[nb + 3];
        *(float4*)((float*)Cout + (size_t)row * Nn + nb) = st;
      }
    }
  }
#undef STG
#undef RDA
#undef RDB
#undef MM
#undef WLG
#undef WVM6
#undef WVM0
#undef BAR
#undef PRIO1
#undef PRIO0
}

// ---------------- kv partials: per (b,h,chunk-of-512-rows): kv[d][e] += k'[n][d]*v[n][e] ----------------
__global__ __launch_bounds__(256) void kv_ksum(const u16* __restrict__ qkv,
                                               float* __restrict__ kvpart,
                                               float* __restrict__ kspart) {
  const int bh = blockIdx.x >> 3;
  const int chunk = blockIdx.x & 7;
  const int b = bh >> 4, h = bh & 15;
  __shared__ u16 kf[64 * 64];
  __shared__ u16 vf[64 * 64];
  const int tid = threadIdx.x;
  const int d0 = (tid & 15) << 2;
  const int e0 = (tid >> 4) << 2;
  float acc[4][4] = {};
  float ks[4] = {0.f, 0.f, 0.f, 0.f};
  const u16* kbase = qkv + (size_t)(b * SEQ) * NQKV + DIM     + h * DHEAD;
  const u16* vbase = qkv + (size_t)(b * SEQ) * NQKV + 2 * DIM + h * DHEAD;
  for (int r0 = chunk * 512; r0 < chunk * 512 + 512; r0 += 64) {
    __syncthreads();
    for (int s = tid; s < 512; s += 256) {
      const int r = s >> 3, co = (s & 7) << 3;
      *(s16x8*)&kf[r * 64 + co] = *(const s16x8*)(kbase + (size_t)(r0 + r) * NQKV + co);
      *(s16x8*)&vf[r * 64 + co] = *(const s16x8*)(vbase + (size_t)(r0 + r) * NQKV + co);
    }
    __syncthreads();
    for (int n = 0; n < 64; n++) {
      const s16x4 ka = *(const s16x4*)&kf[n * 64 + d0];
      const s16x4 va = *(const s16x4*)&vf[n * 64 + e0];
      float kx[4], vx[4];
#pragma unroll
      for (int i = 0; i < 4; i++) { kx[i] = bf2f((u16)ka[i]); vx[i] = bf2f((u16)va[i]); }
#pragma unroll
      for (int i = 0; i < 4; i++)
#pragma unroll
        for (int j = 0; j < 4; j++) acc[i][j] += kx[i] * vx[j];
      if (e0 == 0) {
#pragma unroll
        for (int i = 0; i < 4; i++) ks[i] += kx[i];
      }
    }
  }
  float* outp = kvpart + (size_t)blockIdx.x * 4096;
#pragma unroll
  for (int i = 0; i < 4; i++)
#pragma unroll
    for (int j = 0; j < 4; j++) outp[(d0 + i) * 64 + e0 + j] = acc[i][j];
  if (tid < 16) {
#pragma unroll
    for (int i = 0; i < 4; i++) kspart[(size_t)blockIdx.x * 64 + d0 + i] = ks[i];
  }
}

// ---------------- deterministic partial reduction ----------------
__global__ __launch_bounds__(256) void reduce_kv(const float* __restrict__ kvpart,
                                                 const float* __restrict__ kspart,
                                                 float* __restrict__ kvbuf,
                                                 float* __restrict__ ksumb) {
  const int idx = blockIdx.x * 256 + threadIdx.x;
  if (idx < 64 * 4096) {
    const int bh = idx >> 12, i = idx & 4095;
    float s = 0.f;
#pragma unroll
    for (int c = 0; c < 8; c++) s += kvpart[(size_t)((bh << 3) + c) * 4096 + i];
    kvbuf[idx] = s;
  } else {
    const int idx2 = idx - 64 * 4096;
    if (idx2 < 4096) {
      const int bh = idx2 >> 6, i = idx2 & 63;
      float s = 0.f;
#pragma unroll
      for (int c = 0; c < 8; c++) s += kspart[((bh << 3) + c) * 64 + i];
      ksumb[idx2] = s;
    }
  }
}

// ---------------- attn out: out[n][e] = (q'[n]·kv[:,e]) / (q'[n]·ksum + 1e-6) ----------------
__global__ __launch_bounds__(256) void attn_out_k(const u16* __restrict__ qkv,
                                                  const float* __restrict__ kvbuf,
                                                  const float* __restrict__ ksumb,
                                                  u16* __restrict__ attn) {
  const int bh = blockIdx.x >> 4;
  const int chunk = blockIdx.x & 15;
  const int b = bh >> 4, h = bh & 15;
  __shared__ float kvs[4096];
  __shared__ float kss[64];
  const int tid = threadIdx.x;
  for (int i = tid; i < 1024; i += 256)
    *(float4*)&kvs[i * 4] = *(const float4*)&kvbuf[(size_t)bh * 4096 + i * 4];
  if (tid < 16)
    *(float4*)&kss[tid * 4] = *(const float4*)&ksumb[bh * 64 + tid * 4];
  __syncthreads();
  const int row = b * SEQ + chunk * 256 + tid;
  const u16* qrow = qkv + (size_t)row * NQKV + h * DHEAD;
  float qv[64];
#pragma unroll
  for (int i = 0; i < 8; i++) {
    const s16x8 qr = *(const s16x8*)(qrow + i * 8);
#pragma unroll
    for (int q = 0; q < 8; q++) qv[i * 8 + q] = bf2f((u16)qr[q]);
  }
  float norm = 1e-6f;
#pragma unroll
  for (int d = 0; d < 64; d++) norm += qv[d] * kss[d];
  const float scale = 1.f / norm;
  u16* orow = attn + (size_t)row * DIM + h * DHEAD;
  for (int e4 = 0; e4 < 16; e4++) {
    float ax = 0.f, ay = 0.f, az = 0.f, aw = 0.f;
#pragma unroll
    for (int d = 0; d < 64; d++) {
      const float4 kq = *(const float4*)&kvs[d * 64 + e4 * 4];
      const float qd = qv[d];
      ax += qd * kq.x; ay += qd * kq.y; az += qd * kq.z; aw += qd * kq.w;
    }
    ushort4 st;
    st.x = f2bf(ax * scale); st.y = f2bf(ay * scale);
    st.z = f2bf(az * scale); st.w = f2bf(aw * scale);
    *(ushort4*)(orow + e4 * 4) = st;
  }
}

extern "C" void kernel_launch(void* const* d_in, const int* in_sizes, int n_in,
                              void* d_out, int out_size, void* d_ws, size_t ws_size,
                              hipStream_t stream) {
  (void)in_sizes; (void)n_in; (void)out_size; (void)ws_size;
  const float* x     = (const float*)d_in[0];
  const float* Wqkv  = (const float*)d_in[1];
  const float* Wf    = (const float*)d_in[2];
  const float* bfv   = (const float*)d_in[3];
  const float* Wout  = (const float*)d_in[4];
  const float* bout  = (const float*)d_in[5];
  float* out = (float*)d_out;
  char* ws = (char*)d_ws;

  u16*   wqkvT = (u16*)(ws + 0);              // 3072*1024 bf16   = 6,291,456 B
  u16*   woutT = (u16*)(ws + 6291456);        // 1024*1024 bf16   = 2,097,152 B
  u16*   xb    = (u16*)(ws + 8388608);        // 16384*1024 bf16  = 33,554,432 B
  u16*   qkvb  = (u16*)(ws + 41943040);       // 16384*3072 bf16  = 100,663,296 B
  u16*   attn  = (u16*)(ws + 142606336);      // 16384*1024 bf16  = 33,554,432 B
  float* kvp   = (float*)(ws + 176160768);    // 512*4096 f32     = 8,388,608 B
  float* ksp   = (float*)(ws + 184549376);    // 512*64 f32       = 131,072 B
  float* kvbuf = (float*)(ws + 184680448);    // 64*4096 f32      = 1,048,576 B
  float* ksumb = (float*)(ws + 185729024);    // 64*64 f32        = 16,384 B

  cast_f32_bf16<<<2048, 256, 0, stream>>>(x, xb, MROWS * DIM);
  fold_qk<<<32, 256, 0, stream>>>(Wqkv, Wf, wqkvT);
  transpose_cast<<<256, 256, 0, stream>>>(Wqkv, NQKV, 2 * DIM, wqkvT + (size_t)2 * DIM * DIM, DIM);
  transpose_cast<<<256, 256, 0, stream>>>(Wout, DIM, 0, woutT, DIM);
  gemm8p<1><<<(MROWS / 256) * (NQKV / 256), 512, 0, stream>>>(xb, wqkvT, qkvb, bfv,
                                                              NQKV, DIM);
  kv_ksum<<<64 * 8, 256, 0, stream>>>(qkvb, kvp, ksp);
  reduce_kv<<<(64 * 4096 + 64 * 64 + 255) / 256, 256, 0, stream>>>(kvp, ksp, kvbuf, ksumb);
  attn_out_k<<<64 * 16, 256, 0, stream>>>(qkvb, kvbuf, ksumb, attn);
  gemm8p<2><<<(MROWS / 256) * (DIM / 256), 512, 0, stream>>>(attn, woutT, out, bout,
                                                             DIM, DIM);
}

// Round 5
// 367.986 us; speedup vs baseline: 1.3098x; 1.0742x over previous
//
#include <hip/hip_runtime.h>
#include <hip/hip_bf16.h>
#include <stdint.h>

#define HEADS 16
#define DHEAD 64
#define DIM   1024
#define SEQ   4096
#define BATCH 4
#define MROWS (BATCH * SEQ)   // 16384
#define NQKV  (3 * DIM)       // 3072

typedef short  s16x8 __attribute__((ext_vector_type(8)));
typedef short  s16x4 __attribute__((ext_vector_type(4)));
typedef float  f32x4 __attribute__((ext_vector_type(4)));
typedef unsigned short u16;

__device__ __forceinline__ u16 f2bf(float f) {
  union { float f; uint32_t u; } v; v.f = f;
  uint32_t r = v.u + 0x7fffu + ((v.u >> 16) & 1u);  // RNE
  return (u16)(r >> 16);
}
__device__ __forceinline__ float bf2f(u16 h) {
  union { uint32_t u; float f; } v; v.u = ((uint32_t)h) << 16;
  return v.f;
}

// async global->LDS, 16B per lane; LDS dest is wave-uniform base + lane*16
__device__ __forceinline__ void gload_lds16(const void* g, void* l) {
  __builtin_amdgcn_global_load_lds((__attribute__((address_space(1))) void*)(g),
                                   (__attribute__((address_space(3))) void*)(l),
                                   16, 0, 0);
}

// ---------------- cast fp32 -> bf16 ----------------
__global__ __launch_bounds__(256) void cast_f32_bf16(const float* __restrict__ src,
                                                     u16* __restrict__ dst, int n) {
  int i = (blockIdx.x * 256 + threadIdx.x) * 4;
  const int stride = gridDim.x * 256 * 4;
  for (; i < n; i += stride) {
    float4 f = *(const float4*)(src + i);
    ushort4 o;
    o.x = f2bf(f.x); o.y = f2bf(f.y); o.z = f2bf(f.z); o.w = f2bf(f.w);
    *(ushort4*)(dst + i) = o;
  }
}

// ---------------- fold W_f into q/k blocks of W_qkv, store transposed bf16 ----------------
__global__ __launch_bounds__(256) void fold_qk(const float* __restrict__ Wqkv,
                                               const float* __restrict__ Wf,
                                               u16* __restrict__ WqkvT) {
  const int reg = blockIdx.x >> 4;   // 0 = q, 1 = k
  const int h   = blockIdx.x & 15;
  const int base = reg * DIM + h * DHEAD;
  __shared__ float wf[64 * 64];
  __shared__ float wc[64 * 64];
  const int tid = threadIdx.x;
  for (int i = tid; i < 4096; i += 256) wf[i] = Wf[i];
  const int j  = tid & 63;
  const int kq = tid >> 6;
  for (int kc = 0; kc < DIM; kc += 64) {
    __syncthreads();
    for (int i = tid; i < 4096; i += 256) {
      const int r = i >> 6, c = i & 63;
      wc[r * 64 + c] = Wqkv[(size_t)(kc + r) * NQKV + base + c];
    }
    __syncthreads();
    for (int ki = 0; ki < 16; ki++) {
      const int k = kq * 16 + ki;
      float s = 0.f;
#pragma unroll
      for (int d = 0; d < 64; d++) s += wc[k * 64 + d] * wf[d * 64 + j];
      WqkvT[(size_t)(base + j) * DIM + kc + k] = f2bf(s);
    }
  }
}

// ---------------- transpose + cast: dst[n][k] = src[k][colOff + n] ----------------
__global__ __launch_bounds__(256) void transpose_cast(const float* __restrict__ src,
                                                      int srcStride, int colOff,
                                                      u16* __restrict__ dst, int Nt) {
  __shared__ float t[64][65];
  const int ntiles = Nt >> 6;
  const int n0 = (blockIdx.x % ntiles) * 64;
  const int k0 = (blockIdx.x / ntiles) * 64;
  for (int i = threadIdx.x; i < 4096; i += 256) {
    const int r = i >> 6, c = i & 63;
    t[r][c] = src[(size_t)(k0 + r) * srcStride + colOff + n0 + c];
  }
  __syncthreads();
  for (int i = threadIdx.x; i < 4096; i += 256) {
    const int r = i & 63, c = i >> 6;
    dst[(size_t)(n0 + c) * DIM + k0 + r] = f2bf(t[r][c]);
  }
}

// ---------------- 256x256 8-phase MFMA GEMM (unchanged from R4) ----------------
template <int EPI>
__global__ __launch_bounds__(512, 2) void gemm8p(const u16* __restrict__ A,
                                                 const u16* __restrict__ Bt,
                                                 void* __restrict__ Cout,
                                                 const float* __restrict__ bias,
                                                 int Nn, int K) {
  __shared__ __align__(16) u16 smem[2][2][2][128 * 64];  // [buf][A0/B1][half] = 128 KiB
  const int tilesN = Nn >> 8;
  const int cpx   = gridDim.x >> 3;
  const int xcd   = blockIdx.x & 7;
  const int local = blockIdx.x >> 3;
  const int bmPerX = cpx / tilesN;
  const int perG = 4 * tilesN;
  const int g = local / perG, rrm = local % perG;
  const int bm = xcd * bmPerX + g * 4 + rrm / tilesN;
  const int bn = rrm % tilesN;
  const int m0 = bm << 8, n0 = bn << 8;

  const int tid  = threadIdx.x;
  const int lane = tid & 63;
  const int w    = tid >> 6;
  const int wr = w >> 2, wcn = w & 3;
  const int lrow = lane & 15;
  const int hi   = lane >> 4;
  const int sx   = lrow & 7;

  const int srow  = tid >> 3;
  const int pslot = tid & 7;
  const int gk    = (pslot ^ (srow & 7)) << 3;
  const u16* aBase = A  + (size_t)m0 * K + gk;
  const u16* bBase = Bt + (size_t)n0 * K + gk;

#define STG(buf, op, half, kt, gb)                                             \
  { const u16* s0_ = (gb) + (size_t)((half) * 128 + srow) * K + (kt) * 64;     \
    char* d0_ = (char*)&smem[buf][op][half][0] + tid * 16;                     \
    gload_lds16(s0_, d0_);                                                     \
    gload_lds16(s0_ + (size_t)64 * K, d0_ + 8192); }

#define RDA(buf, dst, mbase)                                                   \
  _Pragma("unroll") for (int mi_ = 0; mi_ < 4; mi_++)                          \
  _Pragma("unroll") for (int kk_ = 0; kk_ < 2; kk_++) {                        \
    const int r_ = ((mbase) + mi_) * 16 + lrow;                                \
    dst[mi_][kk_] = *(const s16x8*)&smem[buf][0][wr]                           \
                        [r_ * 64 + ((kk_ * 4 + hi) ^ sx) * 8]; }

#define RDB(buf, dst, nbase)                                                   \
  _Pragma("unroll") for (int nj_ = 0; nj_ < 2; nj_++)                          \
  _Pragma("unroll") for (int kk_ = 0; kk_ < 2; kk_++) {                        \
    const int r_ = (wcn & 1) * 64 + ((nbase) + nj_) * 16 + lrow;               \
    dst[nj_][kk_] = *(const s16x8*)&smem[buf][1][wcn >> 1]                     \
                        [r_ * 64 + ((kk_ * 4 + hi) ^ sx) * 8]; }

#define MM(mbase, nbase, areg, breg)                                           \
  _Pragma("unroll") for (int mi_ = 0; mi_ < 4; mi_++)                          \
  _Pragma("unroll") for (int nj_ = 0; nj_ < 2; nj_++)                          \
  _Pragma("unroll") for (int kk_ = 0; kk_ < 2; kk_++)                          \
    acc[(mbase) + mi_][(nbase) + nj_] = __builtin_amdgcn_mfma_f32_16x16x32_bf16( \
        breg[nj_][kk_], areg[mi_][kk_], acc[(mbase) + mi_][(nbase) + nj_], 0, 0, 0);

#define WLG  asm volatile("s_waitcnt lgkmcnt(0)" ::: "memory")
#define WVM6 asm volatile("s_waitcnt vmcnt(6)" ::: "memory")
#define WVM0 asm volatile("s_waitcnt vmcnt(0)" ::: "memory")
#define BAR  __builtin_amdgcn_s_barrier()
#define PRIO1 __builtin_amdgcn_s_setprio(1)
#define PRIO0 __builtin_amdgcn_s_setprio(0)

  f32x4 acc[8][4] = {};
  const int NT  = K >> 6;
  const int NIT = NT >> 1;

  STG(0, 0, 0, 0, aBase); STG(0, 0, 1, 0, aBase);
  STG(0, 1, 0, 0, bBase); STG(0, 1, 1, 0, bBase);
  STG(1, 0, 0, 1, aBase); STG(1, 0, 1, 1, aBase);
  STG(1, 1, 0, 1, bBase); STG(1, 1, 1, 1, bBase);
  WVM6; BAR;

  for (int it = 0; it < NIT; ++it) {
    const int tE = 2 * it + 2, tO = 2 * it + 3;
    const bool pf = (tE < NT);
    s16x8 a[4][2], bl[2][2], bh[2][2];
    RDA(0, a, 0); RDB(0, bl, 0);
    BAR; WLG;
    PRIO1; MM(0, 0, a, bl); PRIO0;
    BAR;
    RDB(0, bh, 2);
    BAR; WLG;
    PRIO1; MM(0, 2, a, bh); PRIO0;
    BAR;
    RDA(0, a, 4);
    if (pf) STG(0, 1, 0, tE, bBase);
    BAR; WLG;
    PRIO1; MM(4, 2, a, bh); PRIO0;
    BAR;
    if (pf) { STG(0, 1, 1, tE, bBase); STG(0, 0, 0, tE, aBase); }
    BAR;
    if (pf) { WVM6; } else { WVM0; }
    PRIO1; MM(4, 0, a, bl); PRIO0;
    BAR;
    RDA(1, a, 0); RDB(1, bl, 0);
    if (pf) STG(0, 0, 1, tE, aBase);
    BAR; WLG;
    PRIO1; MM(0, 0, a, bl); PRIO0;
    BAR;
    RDB(1, bh, 2);
    BAR; WLG;
    PRIO1; MM(0, 2, a, bh); PRIO0;
    BAR;
    RDA(1, a, 4);
    if (pf) { STG(1, 1, 0, tO, bBase); STG(1, 1, 1, tO, bBase); }
    BAR; WLG;
    PRIO1; MM(4, 2, a, bh); PRIO0;
    BAR;
    if (pf) { STG(1, 0, 0, tO, aBase); STG(1, 0, 1, tO, aBase); }
    BAR;
    if (pf) { WVM6; } else { WVM0; }
    PRIO1; MM(4, 0, a, bl); PRIO0;
    BAR;
  }

  const int mrow = m0 + wr * 128 + lrow;
  const int nb0  = n0 + wcn * 64 + (hi << 2);
#pragma unroll
  for (int mi = 0; mi < 8; mi++) {
    const int row = mrow + mi * 16;
#pragma unroll
    for (int nj = 0; nj < 4; nj++) {
      const int nb = nb0 + nj * 16;
      float v0 = acc[mi][nj][0], v1 = acc[mi][nj][1];
      float v2 = acc[mi][nj][2], v3 = acc[mi][nj][3];
      if (EPI == 1) {
        if (nb < 2 * DIM) {
          const int bb = nb & 63;
          v0 += bias[bb];     v1 += bias[bb + 1];
          v2 += bias[bb + 2]; v3 += bias[bb + 3];
          v0 = v0 > 0.f ? v0 : 0.f;  v1 = v1 > 0.f ? v1 : 0.f;
          v2 = v2 > 0.f ? v2 : 0.f;  v3 = v3 > 0.f ? v3 : 0.f;
        }
        uint2 st;
        st.x = (uint32_t)f2bf(v0) | ((uint32_t)f2bf(v1) << 16);
        st.y = (uint32_t)f2bf(v2) | ((uint32_t)f2bf(v3) << 16);
        *(uint2*)((u16*)Cout + (size_t)row * Nn + nb) = st;
      } else {
        float4 st;
        st.x = v0 + bias[nb];     st.y = v1 + bias[nb + 1];
        st.z = v2 + bias[nb + 2]; st.w = v3 + bias[nb + 3];
        *(float4*)((float*)Cout + (size_t)row * Nn + nb) = st;
      }
    }
  }
#undef STG
#undef RDA
#undef RDB
#undef MM
#undef WLG
#undef WVM6
#undef WVM0
#undef BAR
#undef PRIO1
#undef PRIO0
}

// ---------------- kv partials (unchanged) ----------------
__global__ __launch_bounds__(256) void kv_ksum(const u16* __restrict__ qkv,
                                               float* __restrict__ kvpart,
                                               float* __restrict__ kspart) {
  const int bh = blockIdx.x >> 3;
  const int chunk = blockIdx.x & 7;
  const int b = bh >> 4, h = bh & 15;
  __shared__ u16 kf[64 * 64];
  __shared__ u16 vf[64 * 64];
  const int tid = threadIdx.x;
  const int d0 = (tid & 15) << 2;
  const int e0 = (tid >> 4) << 2;
  float acc[4][4] = {};
  float ks[4] = {0.f, 0.f, 0.f, 0.f};
  const u16* kbase = qkv + (size_t)(b * SEQ) * NQKV + DIM     + h * DHEAD;
  const u16* vbase = qkv + (size_t)(b * SEQ) * NQKV + 2 * DIM + h * DHEAD;
  for (int r0 = chunk * 512; r0 < chunk * 512 + 512; r0 += 64) {
    __syncthreads();
    for (int s = tid; s < 512; s += 256) {
      const int r = s >> 3, co = (s & 7) << 3;
      *(s16x8*)&kf[r * 64 + co] = *(const s16x8*)(kbase + (size_t)(r0 + r) * NQKV + co);
      *(s16x8*)&vf[r * 64 + co] = *(const s16x8*)(vbase + (size_t)(r0 + r) * NQKV + co);
    }
    __syncthreads();
    for (int n = 0; n < 64; n++) {
      const s16x4 ka = *(const s16x4*)&kf[n * 64 + d0];
      const s16x4 va = *(const s16x4*)&vf[n * 64 + e0];
      float kx[4], vx[4];
#pragma unroll
      for (int i = 0; i < 4; i++) { kx[i] = bf2f((u16)ka[i]); vx[i] = bf2f((u16)va[i]); }
#pragma unroll
      for (int i = 0; i < 4; i++)
#pragma unroll
        for (int j = 0; j < 4; j++) acc[i][j] += kx[i] * vx[j];
      if (e0 == 0) {
#pragma unroll
        for (int i = 0; i < 4; i++) ks[i] += kx[i];
      }
    }
  }
  float* outp = kvpart + (size_t)blockIdx.x * 4096;
#pragma unroll
  for (int i = 0; i < 4; i++)
#pragma unroll
    for (int j = 0; j < 4; j++) outp[(d0 + i) * 64 + e0 + j] = acc[i][j];
  if (tid < 16) {
#pragma unroll
    for (int i = 0; i < 4; i++) kspart[(size_t)blockIdx.x * 64 + d0 + i] = ks[i];
  }
}

// ---------------- deterministic partial reduction (unchanged) ----------------
__global__ __launch_bounds__(256) void reduce_kv(const float* __restrict__ kvpart,
                                                 const float* __restrict__ kspart,
                                                 float* __restrict__ kvbuf,
                                                 float* __restrict__ ksumb) {
  const int idx = blockIdx.x * 256 + threadIdx.x;
  if (idx < 64 * 4096) {
    const int bh = idx >> 12, i = idx & 4095;
    float s = 0.f;
#pragma unroll
    for (int c = 0; c < 8; c++) s += kvpart[(size_t)((bh << 3) + c) * 4096 + i];
    kvbuf[idx] = s;
  } else {
    const int idx2 = idx - 64 * 4096;
    if (idx2 < 4096) {
      const int bh = idx2 >> 6, i = idx2 & 63;
      float s = 0.f;
#pragma unroll
      for (int c = 0; c < 8; c++) s += kspart[((bh << 3) + c) * 64 + i];
      ksumb[idx2] = s;
    }
  }
}

// ---------------- attn out via MFMA: out[n][e] = (q[n]·kv[:,e]) / (q[n]·ksum + 1e-6) ----------------
// Per block: one (b,h) and one 256-row chunk. A = q rows (direct global->VGPR frags),
// B = [kv | ksum | 0] as hi/lo bf16 split (fp32-equivalent), LDS XOR-swizzled.
// D col 64 = normalizer; broadcast via nrm[], divide, pack bf16.
__global__ __launch_bounds__(256) void attn_mfma(const u16* __restrict__ qkv,
                                                 const float* __restrict__ kvbuf,
                                                 const float* __restrict__ ksumb,
                                                 u16* __restrict__ attn) {
  const int bh = blockIdx.x >> 4;        // 0..63
  const int mc = blockIdx.x & 15;        // 256-row chunk
  const int b = bh >> 4, h = bh & 15;
  __shared__ u16 BT[2][80][64];          // [hi/lo][e-row][swizzled d], 20.5 KB
  __shared__ float nrm[256];
  const int tid  = threadIdx.x;
  const int lane = tid & 63;
  const int w    = tid >> 6;
  const int lrow = lane & 15;
  const int hi   = lane >> 4;

  // stage B = [kv | ksum | 0] hi/lo; swizzle: 16B slot (d>>3) ^ (e&7)
#pragma unroll
  for (int s = 0; s < 20; s++) {
    const int idx = tid + 256 * s;       // 0..5119
    const int e = idx >> 6, d = idx & 63;
    float v;
    if (e < 64)       v = kvbuf[(size_t)bh * 4096 + d * 64 + e];
    else if (e == 64) v = ksumb[bh * 64 + d];
    else              v = 0.f;
    const u16 vh = f2bf(v);
    const u16 vl = f2bf(v - bf2f(vh));
    const int off = e * 64 + (((d >> 3) ^ (e & 7)) << 3) + (d & 7);
    BT[0][0][off] = vh;
    BT[1][0][off] = vl;
  }

  // q fragments: rows mc*256 + w*64 + mi*16 + lrow, elems kk*32 + hi*8 .. +7
  const int rloc = w * 64 + lrow;        // + mi*16
  const u16* qbase = qkv + (size_t)(b * SEQ + mc * 256 + rloc) * NQKV + h * DHEAD + hi * 8;
  s16x8 af[4][2];
#pragma unroll
  for (int mi = 0; mi < 4; mi++)
#pragma unroll
    for (int kk = 0; kk < 2; kk++)
      af[mi][kk] = *(const s16x8*)(qbase + (size_t)(mi * 16) * NQKV + kk * 32);

  __syncthreads();

  f32x4 acc[4][5] = {};
#pragma unroll
  for (int wv = 0; wv < 2; wv++) {
#pragma unroll
    for (int jb = 0; jb < 5; jb++) {
      const int erow = jb * 16 + lrow;
      const int sx = erow & 7;
      s16x8 bq0 = *(const s16x8*)&BT[wv][erow][((0 * 4 + hi) ^ sx) << 3];
      s16x8 bq1 = *(const s16x8*)&BT[wv][erow][((1 * 4 + hi) ^ sx) << 3];
#pragma unroll
      for (int mi = 0; mi < 4; mi++) {
        acc[mi][jb] = __builtin_amdgcn_mfma_f32_16x16x32_bf16(bq0, af[mi][0], acc[mi][jb], 0, 0, 0);
        acc[mi][jb] = __builtin_amdgcn_mfma_f32_16x16x32_bf16(bq1, af[mi][1], acc[mi][jb], 0, 0, 0);
      }
    }
  }

  // normalizer = column 64 (jb=4, hi==0, reg 0)
  if (hi == 0) {
#pragma unroll
    for (int mi = 0; mi < 4; mi++) nrm[rloc + mi * 16] = acc[mi][4][0] + 1e-6f;
  }
  __syncthreads();

  u16* obase = attn + (size_t)(b * SEQ + mc * 256 + rloc) * DIM + h * DHEAD + hi * 4;
#pragma unroll
  for (int mi = 0; mi < 4; mi++) {
    const float sc = 1.f / nrm[rloc + mi * 16];
#pragma unroll
    for (int jb = 0; jb < 4; jb++) {
      uint2 st;
      st.x = (uint32_t)f2bf(acc[mi][jb][0] * sc) | ((uint32_t)f2bf(acc[mi][jb][1] * sc) << 16);
      st.y = (uint32_t)f2bf(acc[mi][jb][2] * sc) | ((uint32_t)f2bf(acc[mi][jb][3] * sc) << 16);
      *(uint2*)(obase + (size_t)(mi * 16) * DIM + jb * 16) = st;
    }
  }
}

extern "C" void kernel_launch(void* const* d_in, const int* in_sizes, int n_in,
                              void* d_out, int out_size, void* d_ws, size_t ws_size,
                              hipStream_t stream) {
  (void)in_sizes; (void)n_in; (void)out_size; (void)ws_size;
  const float* x     = (const float*)d_in[0];
  const float* Wqkv  = (const float*)d_in[1];
  const float* Wf    = (const float*)d_in[2];
  const float* bfv   = (const float*)d_in[3];
  const float* Wout  = (const float*)d_in[4];
  const float* bout  = (const float*)d_in[5];
  float* out = (float*)d_out;
  char* ws = (char*)d_ws;

  u16*   wqkvT = (u16*)(ws + 0);              // 3072*1024 bf16   = 6,291,456 B
  u16*   woutT = (u16*)(ws + 6291456);        // 1024*1024 bf16   = 2,097,152 B
  u16*   xb    = (u16*)(ws + 8388608);        // 16384*1024 bf16  = 33,554,432 B
  u16*   qkvb  = (u16*)(ws + 41943040);       // 16384*3072 bf16  = 100,663,296 B
  u16*   attn  = (u16*)(ws + 142606336);      // 16384*1024 bf16  = 33,554,432 B
  float* kvp   = (float*)(ws + 176160768);    // 512*4096 f32     = 8,388,608 B
  float* ksp   = (float*)(ws + 184549376);    // 512*64 f32       = 131,072 B
  float* kvbuf = (float*)(ws + 184680448);    // 64*4096 f32      = 1,048,576 B
  float* ksumb = (float*)(ws + 185729024);    // 64*64 f32        = 16,384 B

  cast_f32_bf16<<<2048, 256, 0, stream>>>(x, xb, MROWS * DIM);
  fold_qk<<<32, 256, 0, stream>>>(Wqkv, Wf, wqkvT);
  transpose_cast<<<256, 256, 0, stream>>>(Wqkv, NQKV, 2 * DIM, wqkvT + (size_t)2 * DIM * DIM, DIM);
  transpose_cast<<<256, 256, 0, stream>>>(Wout, DIM, 0, woutT, DIM);
  gemm8p<1><<<(MROWS / 256) * (NQKV / 256), 512, 0, stream>>>(xb, wqkvT, qkvb, bfv,
                                                              NQKV, DIM);
  kv_ksum<<<64 * 8, 256, 0, stream>>>(qkvb, kvp, ksp);
  reduce_kv<<<(64 * 4096 + 64 * 64 + 255) / 256, 256, 0, stream>>>(kvp, ksp, kvbuf, ksumb);
  attn_mfma<<<64 * 16, 256, 0, stream>>>(qkvb, kvbuf, ksumb, attn);
  gemm8p<2><<<(MROWS / 256) * (DIM / 256), 512, 0, stream>>>(attn, woutT, out, bout,
                                                             DIM, DIM);
}

// Round 6
// 258.020 us; speedup vs baseline: 1.8680x; 1.4262x over previous
//
#include <hip/hip_runtime.h>
#include <hip/hip_bf16.h>
#include <stdint.h>

#define HEADS 16
#define DHEAD 64
#define DIM   1024
#define SEQ   4096
#define BATCH 4
#define MROWS (BATCH * SEQ)   // 16384
#define NQKV  (3 * DIM)       // 3072

typedef short  s16x8 __attribute__((ext_vector_type(8)));
typedef short  s16x4 __attribute__((ext_vector_type(4)));
typedef float  f32x4 __attribute__((ext_vector_type(4)));
typedef unsigned short u16;

__device__ __forceinline__ u16 f2bf(float f) {
  union { float f; uint32_t u; } v; v.f = f;
  uint32_t r = v.u + 0x7fffu + ((v.u >> 16) & 1u);  // RNE
  return (u16)(r >> 16);
}
__device__ __forceinline__ float bf2f(u16 h) {
  union { uint32_t u; float f; } v; v.u = ((uint32_t)h) << 16;
  return v.f;
}

// async global->LDS, 16B per lane; LDS dest is wave-uniform base + lane*16
__device__ __forceinline__ void gload_lds16(const void* g, void* l) {
  __builtin_amdgcn_global_load_lds((__attribute__((address_space(1))) void*)(g),
                                   (__attribute__((address_space(3))) void*)(l),
                                   16, 0, 0);
}

// ---------------- cast fp32 -> bf16 ----------------
__global__ __launch_bounds__(256) void cast_f32_bf16(const float* __restrict__ src,
                                                     u16* __restrict__ dst, int n) {
  int i = (blockIdx.x * 256 + threadIdx.x) * 4;
  const int stride = gridDim.x * 256 * 4;
  for (; i < n; i += stride) {
    float4 f = *(const float4*)(src + i);
    ushort4 o;
    o.x = f2bf(f.x); o.y = f2bf(f.y); o.z = f2bf(f.z); o.w = f2bf(f.w);
    *(ushort4*)(dst + i) = o;
  }
}

// ---------------- fold W_f into q/k blocks of W_qkv, store transposed bf16 ----------------
// v2: 256 blocks (32 head-regions x 8 k-chunks of 128), wf column in registers,
// wc via wave-uniform LDS broadcast. Same fp32 math as v1.
__global__ __launch_bounds__(256) void fold_qk(const float* __restrict__ Wqkv,
                                               const float* __restrict__ Wf,
                                               u16* __restrict__ WqkvT) {
  const int rh  = blockIdx.x >> 3;          // 0..31 = (reg,h)
  const int kc  = (blockIdx.x & 7) << 7;    // k-chunk base (128 each)
  const int reg = rh >> 4, h = rh & 15;
  const int base = reg * DIM + h * DHEAD;
  __shared__ float wc[128 * 64];            // 32 KB
  const int tid = threadIdx.x;
  const int j  = tid & 63;
  const int kg = tid >> 6;                  // 0..3 -> k range kg*32..+31
  // stage Wqkv rows kc..kc+127, cols base..base+63 (float4 coalesced)
  for (int i = tid; i < 128 * 16; i += 256) {
    const int r = i >> 4, c4 = (i & 15) << 2;
    *(float4*)&wc[r * 64 + c4] = *(const float4*)&Wqkv[(size_t)(kc + r) * NQKV + base + c4];
  }
  // wf column j -> 64 registers (statically indexed)
  float v[64];
#pragma unroll
  for (int d = 0; d < 64; d++) v[d] = Wf[d * 64 + j];
  __syncthreads();
  u16* dst = WqkvT + (size_t)(base + j) * DIM + kc + kg * 32;
  for (int ki = 0; ki < 32; ki++) {
    const int k = kg * 32 + ki;
    float s = 0.f;
#pragma unroll
    for (int d = 0; d < 64; d++) s += wc[k * 64 + d] * v[d];   // wc: wave-uniform broadcast
    dst[ki] = f2bf(s);
  }
}

// ---------------- transpose + cast: dst[n][k] = src[k][colOff + n] ----------------
__global__ __launch_bounds__(256) void transpose_cast(const float* __restrict__ src,
                                                      int srcStride, int colOff,
                                                      u16* __restrict__ dst, int Nt) {
  __shared__ float t[64][65];
  const int ntiles = Nt >> 6;
  const int n0 = (blockIdx.x % ntiles) * 64;
  const int k0 = (blockIdx.x / ntiles) * 64;
  for (int i = threadIdx.x; i < 4096; i += 256) {
    const int r = i >> 6, c = i & 63;
    t[r][c] = src[(size_t)(k0 + r) * srcStride + colOff + n0 + c];
  }
  __syncthreads();
  for (int i = threadIdx.x; i < 4096; i += 256) {
    const int r = i & 63, c = i >> 6;
    dst[(size_t)(n0 + c) * DIM + k0 + r] = f2bf(t[r][c]);
  }
}

// ---------------- 256x256 8-phase MFMA GEMM (unchanged from R4) ----------------
template <int EPI>
__global__ __launch_bounds__(512, 2) void gemm8p(const u16* __restrict__ A,
                                                 const u16* __restrict__ Bt,
                                                 void* __restrict__ Cout,
                                                 const float* __restrict__ bias,
                                                 int Nn, int K) {
  __shared__ __align__(16) u16 smem[2][2][2][128 * 64];  // [buf][A0/B1][half] = 128 KiB
  const int tilesN = Nn >> 8;
  const int cpx   = gridDim.x >> 3;
  const int xcd   = blockIdx.x & 7;
  const int local = blockIdx.x >> 3;
  const int bmPerX = cpx / tilesN;
  const int perG = 4 * tilesN;
  const int g = local / perG, rrm = local % perG;
  const int bm = xcd * bmPerX + g * 4 + rrm / tilesN;
  const int bn = rrm % tilesN;
  const int m0 = bm << 8, n0 = bn << 8;

  const int tid  = threadIdx.x;
  const int lane = tid & 63;
  const int w    = tid >> 6;
  const int wr = w >> 2, wcn = w & 3;
  const int lrow = lane & 15;
  const int hi   = lane >> 4;
  const int sx   = lrow & 7;

  const int srow  = tid >> 3;
  const int pslot = tid & 7;
  const int gk    = (pslot ^ (srow & 7)) << 3;
  const u16* aBase = A  + (size_t)m0 * K + gk;
  const u16* bBase = Bt + (size_t)n0 * K + gk;

#define STG(buf, op, half, kt, gb)                                             \
  { const u16* s0_ = (gb) + (size_t)((half) * 128 + srow) * K + (kt) * 64;     \
    char* d0_ = (char*)&smem[buf][op][half][0] + tid * 16;                     \
    gload_lds16(s0_, d0_);                                                     \
    gload_lds16(s0_ + (size_t)64 * K, d0_ + 8192); }

#define RDA(buf, dst, mbase)                                                   \
  _Pragma("unroll") for (int mi_ = 0; mi_ < 4; mi_++)                          \
  _Pragma("unroll") for (int kk_ = 0; kk_ < 2; kk_++) {                        \
    const int r_ = ((mbase) + mi_) * 16 + lrow;                                \
    dst[mi_][kk_] = *(const s16x8*)&smem[buf][0][wr]                           \
                        [r_ * 64 + ((kk_ * 4 + hi) ^ sx) * 8]; }

#define RDB(buf, dst, nbase)                                                   \
  _Pragma("unroll") for (int nj_ = 0; nj_ < 2; nj_++)                          \
  _Pragma("unroll") for (int kk_ = 0; kk_ < 2; kk_++) {                        \
    const int r_ = (wcn & 1) * 64 + ((nbase) + nj_) * 16 + lrow;               \
    dst[nj_][kk_] = *(const s16x8*)&smem[buf][1][wcn >> 1]                     \
                        [r_ * 64 + ((kk_ * 4 + hi) ^ sx) * 8]; }

#define MM(mbase, nbase, areg, breg)                                           \
  _Pragma("unroll") for (int mi_ = 0; mi_ < 4; mi_++)                          \
  _Pragma("unroll") for (int nj_ = 0; nj_ < 2; nj_++)                          \
  _Pragma("unroll") for (int kk_ = 0; kk_ < 2; kk_++)                          \
    acc[(mbase) + mi_][(nbase) + nj_] = __builtin_amdgcn_mfma_f32_16x16x32_bf16( \
        breg[nj_][kk_], areg[mi_][kk_], acc[(mbase) + mi_][(nbase) + nj_], 0, 0, 0);

#define WLG  asm volatile("s_waitcnt lgkmcnt(0)" ::: "memory")
#define WVM6 asm volatile("s_waitcnt vmcnt(6)" ::: "memory")
#define WVM0 asm volatile("s_waitcnt vmcnt(0)" ::: "memory")
#define BAR  __builtin_amdgcn_s_barrier()
#define PRIO1 __builtin_amdgcn_s_setprio(1)
#define PRIO0 __builtin_amdgcn_s_setprio(0)

  f32x4 acc[8][4] = {};
  const int NT  = K >> 6;
  const int NIT = NT >> 1;

  STG(0, 0, 0, 0, aBase); STG(0, 0, 1, 0, aBase);
  STG(0, 1, 0, 0, bBase); STG(0, 1, 1, 0, bBase);
  STG(1, 0, 0, 1, aBase); STG(1, 0, 1, 1, aBase);
  STG(1, 1, 0, 1, bBase); STG(1, 1, 1, 1, bBase);
  WVM6; BAR;

  for (int it = 0; it < NIT; ++it) {
    const int tE = 2 * it + 2, tO = 2 * it + 3;
    const bool pf = (tE < NT);
    s16x8 a[4][2], bl[2][2], bh[2][2];
    RDA(0, a, 0); RDB(0, bl, 0);
    BAR; WLG;
    PRIO1; MM(0, 0, a, bl); PRIO0;
    BAR;
    RDB(0, bh, 2);
    BAR; WLG;
    PRIO1; MM(0, 2, a, bh); PRIO0;
    BAR;
    RDA(0, a, 4);
    if (pf) STG(0, 1, 0, tE, bBase);
    BAR; WLG;
    PRIO1; MM(4, 2, a, bh); PRIO0;
    BAR;
    if (pf) { STG(0, 1, 1, tE, bBase); STG(0, 0, 0, tE, aBase); }
    BAR;
    if (pf) { WVM6; } else { WVM0; }
    PRIO1; MM(4, 0, a, bl); PRIO0;
    BAR;
    RDA(1, a, 0); RDB(1, bl, 0);
    if (pf) STG(0, 0, 1, tE, aBase);
    BAR; WLG;
    PRIO1; MM(0, 0, a, bl); PRIO0;
    BAR;
    RDB(1, bh, 2);
    BAR; WLG;
    PRIO1; MM(0, 2, a, bh); PRIO0;
    BAR;
    RDA(1, a, 4);
    if (pf) { STG(1, 1, 0, tO, bBase); STG(1, 1, 1, tO, bBase); }
    BAR; WLG;
    PRIO1; MM(4, 2, a, bh); PRIO0;
    BAR;
    if (pf) { STG(1, 0, 0, tO, aBase); STG(1, 0, 1, tO, aBase); }
    BAR;
    if (pf) { WVM6; } else { WVM0; }
    PRIO1; MM(4, 0, a, bl); PRIO0;
    BAR;
  }

  const int mrow = m0 + wr * 128 + lrow;
  const int nb0  = n0 + wcn * 64 + (hi << 2);
#pragma unroll
  for (int mi = 0; mi < 8; mi++) {
    const int row = mrow + mi * 16;
#pragma unroll
    for (int nj = 0; nj < 4; nj++) {
      const int nb = nb0 + nj * 16;
      float v0 = acc[mi][nj][0], v1 = acc[mi][nj][1];
      float v2 = acc[mi][nj][2], v3 = acc[mi][nj][3];
      if (EPI == 1) {
        if (nb < 2 * DIM) {
          const int bb = nb & 63;
          v0 += bias[bb];     v1 += bias[bb + 1];
          v2 += bias[bb + 2]; v3 += bias[bb + 3];
          v0 = v0 > 0.f ? v0 : 0.f;  v1 = v1 > 0.f ? v1 : 0.f;
          v2 = v2 > 0.f ? v2 : 0.f;  v3 = v3 > 0.f ? v3 : 0.f;
        }
        uint2 st;
        st.x = (uint32_t)f2bf(v0) | ((uint32_t)f2bf(v1) << 16);
        st.y = (uint32_t)f2bf(v2) | ((uint32_t)f2bf(v3) << 16);
        *(uint2*)((u16*)Cout + (size_t)row * Nn + nb) = st;
      } else {
        float4 st;
        st.x = v0 + bias[nb];     st.y = v1 + bias[nb + 1];
        st.z = v2 + bias[nb + 2]; st.w = v3 + bias[nb + 3];
        *(float4*)((float*)Cout + (size_t)row * Nn + nb) = st;
      }
    }
  }
#undef STG
#undef RDA
#undef RDB
#undef MM
#undef WLG
#undef WVM6
#undef WVM0
#undef BAR
#undef PRIO1
#undef PRIO0
}

// ---------------- kv partials via MFMA: kv[d][e] = sum_n k[n][d] * v[n][e] ----------------
// Transposed LDS staging (XOR swizzle slot^(row&7)); B gets 16 extra rows with
// e=64 all-ones -> column 64 of D = k-sum. Operand convention mirrors attn_mfma
// (HW-verified): mfma(vf, kf, acc) -> row = kf lane (d), col = (hi,reg) of vf (e).
__global__ __launch_bounds__(256) void kv_ksum_mfma(const u16* __restrict__ qkv,
                                                    float* __restrict__ kvpart,
                                                    float* __restrict__ kspart) {
  const int bh = blockIdx.x >> 3;
  const int chunk = blockIdx.x & 7;
  const int b = bh >> 4, h = bh & 15;
  __shared__ u16 kT[64 * 64];   // [d][n swizzled]  8 KB
  __shared__ u16 vT[80 * 64];   // [e][n swizzled] 10 KB (rows 64..79 static)
  const int tid  = threadIdx.x;
  const int lane = tid & 63;
  const int w    = tid >> 6;    // wave = d-tile (0..3)
  const int lrow = lane & 15;
  const int hi   = lane >> 4;

  // static rows: e=64 -> 1.0 (bf16 0x3F80), e=65..79 -> 0
  for (int i = tid; i < 16 * 64; i += 256) {
    const int r = 64 + (i >> 6), n = i & 63;
    vT[r * 64 + (((n >> 3) ^ (r & 7)) << 3) + (n & 7)] = (r == 64) ? (u16)0x3F80 : (u16)0;
  }

  f32x4 acc[5] = {};
  const u16* kbase = qkv + (size_t)(b * SEQ) * NQKV + DIM     + h * DHEAD;
  const u16* vbase = qkv + (size_t)(b * SEQ) * NQKV + 2 * DIM + h * DHEAD;

  for (int r0 = chunk * 512; r0 < chunk * 512 + 512; r0 += 64) {
    __syncthreads();
    for (int s = tid; s < 512; s += 256) {
      const int r  = s >> 3;          // n within chunk
      const int c0 = (s & 7) << 3;    // d base
      const s16x8 k8 = *(const s16x8*)(kbase + (size_t)(r0 + r) * NQKV + c0);
      const s16x8 v8 = *(const s16x8*)(vbase + (size_t)(r0 + r) * NQKV + c0);
      const int slot = r >> 3, nb = r & 7;
#pragma unroll
      for (int q = 0; q < 8; q++) {
        const int d = c0 + q;
        const int off = d * 64 + ((slot ^ (d & 7)) << 3) + nb;
        kT[off] = (u16)k8[q];
        vT[off] = (u16)v8[q];
      }
    }
    __syncthreads();
#pragma unroll
    for (int kk = 0; kk < 2; kk++) {
      const int drow = w * 16 + lrow;
      const s16x8 kf = *(const s16x8*)&kT[drow * 64 + (((kk * 4 + hi) ^ (drow & 7)) << 3)];
#pragma unroll
      for (int et = 0; et < 5; et++) {
        const int erow = et * 16 + lrow;
        const s16x8 vf = *(const s16x8*)&vT[erow * 64 + (((kk * 4 + hi) ^ (erow & 7)) << 3)];
        acc[et] = __builtin_amdgcn_mfma_f32_16x16x32_bf16(vf, kf, acc[et], 0, 0, 0);
      }
    }
  }

  const int d = w * 16 + lrow;
  float* outp = kvpart + (size_t)blockIdx.x * 4096;
#pragma unroll
  for (int et = 0; et < 4; et++)
    *(f32x4*)&outp[d * 64 + et * 16 + hi * 4] = acc[et];
  if (hi == 0) kspart[(size_t)blockIdx.x * 64 + d] = acc[4][0];
}

// ---------------- deterministic partial reduction (unchanged) ----------------
__global__ __launch_bounds__(256) void reduce_kv(const float* __restrict__ kvpart,
                                                 const float* __restrict__ kspart,
                                                 float* __restrict__ kvbuf,
                                                 float* __restrict__ ksumb) {
  const int idx = blockIdx.x * 256 + threadIdx.x;
  if (idx < 64 * 4096) {
    const int bh = idx >> 12, i = idx & 4095;
    float s = 0.f;
#pragma unroll
    for (int c = 0; c < 8; c++) s += kvpart[(size_t)((bh << 3) + c) * 4096 + i];
    kvbuf[idx] = s;
  } else {
    const int idx2 = idx - 64 * 4096;
    if (idx2 < 4096) {
      const int bh = idx2 >> 6, i = idx2 & 63;
      float s = 0.f;
#pragma unroll
      for (int c = 0; c < 8; c++) s += kspart[((bh << 3) + c) * 64 + i];
      ksumb[idx2] = s;
    }
  }
}

// ---------------- attn out via MFMA (unchanged from R5) ----------------
__global__ __launch_bounds__(256) void attn_mfma(const u16* __restrict__ qkv,
                                                 const float* __restrict__ kvbuf,
                                                 const float* __restrict__ ksumb,
                                                 u16* __restrict__ attn) {
  const int bh = blockIdx.x >> 4;        // 0..63
  const int mc = blockIdx.x & 15;        // 256-row chunk
  const int b = bh >> 4, h = bh & 15;
  __shared__ u16 BT[2][80][64];          // [hi/lo][e-row][swizzled d], 20.5 KB
  __shared__ float nrm[256];
  const int tid  = threadIdx.x;
  const int lane = tid & 63;
  const int w    = tid >> 6;
  const int lrow = lane & 15;
  const int hi   = lane >> 4;

#pragma unroll
  for (int s = 0; s < 20; s++) {
    const int idx = tid + 256 * s;       // 0..5119
    const int e = idx >> 6, d = idx & 63;
    float v;
    if (e < 64)       v = kvbuf[(size_t)bh * 4096 + d * 64 + e];
    else if (e == 64) v = ksumb[bh * 64 + d];
    else              v = 0.f;
    const u16 vh = f2bf(v);
    const u16 vl = f2bf(v - bf2f(vh));
    const int off = e * 64 + (((d >> 3) ^ (e & 7)) << 3) + (d & 7);
    BT[0][0][off] = vh;
    BT[1][0][off] = vl;
  }

  const int rloc = w * 64 + lrow;        // + mi*16
  const u16* qbase = qkv + (size_t)(b * SEQ + mc * 256 + rloc) * NQKV + h * DHEAD + hi * 8;
  s16x8 af[4][2];
#pragma unroll
  for (int mi = 0; mi < 4; mi++)
#pragma unroll
    for (int kk = 0; kk < 2; kk++)
      af[mi][kk] = *(const s16x8*)(qbase + (size_t)(mi * 16) * NQKV + kk * 32);

  __syncthreads();

  f32x4 acc[4][5] = {};
#pragma unroll
  for (int wv = 0; wv < 2; wv++) {
#pragma unroll
    for (int jb = 0; jb < 5; jb++) {
      const int erow = jb * 16 + lrow;
      const int sx = erow & 7;
      s16x8 bq0 = *(const s16x8*)&BT[wv][erow][((0 * 4 + hi) ^ sx) << 3];
      s16x8 bq1 = *(const s16x8*)&BT[wv][erow][((1 * 4 + hi) ^ sx) << 3];
#pragma unroll
      for (int mi = 0; mi < 4; mi++) {
        acc[mi][jb] = __builtin_amdgcn_mfma_f32_16x16x32_bf16(bq0, af[mi][0], acc[mi][jb], 0, 0, 0);
        acc[mi][jb] = __builtin_amdgcn_mfma_f32_16x16x32_bf16(bq1, af[mi][1], acc[mi][jb], 0, 0, 0);
      }
    }
  }

  if (hi == 0) {
#pragma unroll
    for (int mi = 0; mi < 4; mi++) nrm[rloc + mi * 16] = acc[mi][4][0] + 1e-6f;
  }
  __syncthreads();

  u16* obase = attn + (size_t)(b * SEQ + mc * 256 + rloc) * DIM + h * DHEAD + hi * 4;
#pragma unroll
  for (int mi = 0; mi < 4; mi++) {
    const float sc = 1.f / nrm[rloc + mi * 16];
#pragma unroll
    for (int jb = 0; jb < 4; jb++) {
      uint2 st;
      st.x = (uint32_t)f2bf(acc[mi][jb][0] * sc) | ((uint32_t)f2bf(acc[mi][jb][1] * sc) << 16);
      st.y = (uint32_t)f2bf(acc[mi][jb][2] * sc) | ((uint32_t)f2bf(acc[mi][jb][3] * sc) << 16);
      *(uint2*)(obase + (size_t)(mi * 16) * DIM + jb * 16) = st;
    }
  }
}

extern "C" void kernel_launch(void* const* d_in, const int* in_sizes, int n_in,
                              void* d_out, int out_size, void* d_ws, size_t ws_size,
                              hipStream_t stream) {
  (void)in_sizes; (void)n_in; (void)out_size; (void)ws_size;
  const float* x     = (const float*)d_in[0];
  const float* Wqkv  = (const float*)d_in[1];
  const float* Wf    = (const float*)d_in[2];
  const float* bfv   = (const float*)d_in[3];
  const float* Wout  = (const float*)d_in[4];
  const float* bout  = (const float*)d_in[5];
  float* out = (float*)d_out;
  char* ws = (char*)d_ws;

  u16*   wqkvT = (u16*)(ws + 0);              // 3072*1024 bf16   = 6,291,456 B
  u16*   woutT = (u16*)(ws + 6291456);        // 1024*1024 bf16   = 2,097,152 B
  u16*   xb    = (u16*)(ws + 8388608);        // 16384*1024 bf16  = 33,554,432 B
  u16*   qkvb  = (u16*)(ws + 41943040);       // 16384*3072 bf16  = 100,663,296 B
  u16*   attn  = (u16*)(ws + 142606336);      // 16384*1024 bf16  = 33,554,432 B
  float* kvp   = (float*)(ws + 176160768);    // 512*4096 f32     = 8,388,608 B
  float* ksp   = (float*)(ws + 184549376);    // 512*64 f32       = 131,072 B
  float* kvbuf = (float*)(ws + 184680448);    // 64*4096 f32      = 1,048,576 B
  float* ksumb = (float*)(ws + 185729024);    // 64*64 f32        = 16,384 B

  cast_f32_bf16<<<2048, 256, 0, stream>>>(x, xb, MROWS * DIM);
  fold_qk<<<256, 256, 0, stream>>>(Wqkv, Wf, wqkvT);
  transpose_cast<<<256, 256, 0, stream>>>(Wqkv, NQKV, 2 * DIM, wqkvT + (size_t)2 * DIM * DIM, DIM);
  transpose_cast<<<256, 256, 0, stream>>>(Wout, DIM, 0, woutT, DIM);
  gemm8p<1><<<(MROWS / 256) * (NQKV / 256), 512, 0, stream>>>(xb, wqkvT, qkvb, bfv,
                                                              NQKV, DIM);
  kv_ksum_mfma<<<64 * 8, 256, 0, stream>>>(qkvb, kvp, ksp);
  reduce_kv<<<(64 * 4096 + 64 * 64 + 255) / 256, 256, 0, stream>>>(kvp, ksp, kvbuf, ksumb);
  attn_mfma<<<64 * 16, 256, 0, stream>>>(qkvb, kvbuf, ksumb, attn);
  gemm8p<2><<<(MROWS / 256) * (DIM / 256), 512, 0, stream>>>(attn, woutT, out, bout,
                                                             DIM, DIM);
}

// Round 8
// 256.128 us; speedup vs baseline: 1.8818x; 1.0074x over previous
//
#include <hip/hip_runtime.h>
#include <hip/hip_bf16.h>
#include <stdint.h>

#define HEADS 16
#define DHEAD 64
#define DIM   1024
#define SEQ   4096
#define BATCH 4
#define MROWS (BATCH * SEQ)   // 16384
#define NQKV  (3 * DIM)       // 3072

typedef short  s16x8 __attribute__((ext_vector_type(8)));
typedef short  s16x4 __attribute__((ext_vector_type(4)));
typedef float  f32x4 __attribute__((ext_vector_type(4)));
typedef unsigned short u16;

__device__ __forceinline__ u16 f2bf(float f) {
  union { float f; uint32_t u; } v; v.f = f;
  uint32_t r = v.u + 0x7fffu + ((v.u >> 16) & 1u);  // RNE
  return (u16)(r >> 16);
}
__device__ __forceinline__ float bf2f(u16 h) {
  union { uint32_t u; float f; } v; v.u = ((uint32_t)h) << 16;
  return v.f;
}

// async global->LDS, 16B per lane; LDS dest is wave-uniform base + lane*16
__device__ __forceinline__ void gload_lds16(const void* g, void* l) {
  __builtin_amdgcn_global_load_lds((__attribute__((address_space(1))) void*)(g),
                                   (__attribute__((address_space(3))) void*)(l),
                                   16, 0, 0);
}

// ---------------- cast fp32 -> bf16 ----------------
__global__ __launch_bounds__(256) void cast_f32_bf16(const float* __restrict__ src,
                                                     u16* __restrict__ dst, int n) {
  int i = (blockIdx.x * 256 + threadIdx.x) * 4;
  const int stride = gridDim.x * 256 * 4;
  for (; i < n; i += stride) {
    float4 f = *(const float4*)(src + i);
    ushort4 o;
    o.x = f2bf(f.x); o.y = f2bf(f.y); o.z = f2bf(f.z); o.w = f2bf(f.w);
    *(ushort4*)(dst + i) = o;
  }
}

// ---------------- fold W_f into q/k blocks of W_qkv, store transposed bf16 ----------------
// v2: 256 blocks (32 head-regions x 8 k-chunks of 128), wf column in registers,
// wc via wave-uniform LDS broadcast. Same fp32 math as v1.
__global__ __launch_bounds__(256) void fold_qk(const float* __restrict__ Wqkv,
                                               const float* __restrict__ Wf,
                                               u16* __restrict__ WqkvT) {
  const int rh  = blockIdx.x >> 3;          // 0..31 = (reg,h)
  const int kc  = (blockIdx.x & 7) << 7;    // k-chunk base (128 each)
  const int reg = rh >> 4, h = rh & 15;
  const int base = reg * DIM + h * DHEAD;
  __shared__ float wc[128 * 64];            // 32 KB
  const int tid = threadIdx.x;
  const int j  = tid & 63;
  const int kg = tid >> 6;                  // 0..3 -> k range kg*32..+31
  for (int i = tid; i < 128 * 16; i += 256) {
    const int r = i >> 4, c4 = (i & 15) << 2;
    *(float4*)&wc[r * 64 + c4] = *(const float4*)&Wqkv[(size_t)(kc + r) * NQKV + base + c4];
  }
  float v[64];
#pragma unroll
  for (int d = 0; d < 64; d++) v[d] = Wf[d * 64 + j];
  __syncthreads();
  u16* dst = WqkvT + (size_t)(base + j) * DIM + kc + kg * 32;
  for (int ki = 0; ki < 32; ki++) {
    const int k = kg * 32 + ki;
    float s = 0.f;
#pragma unroll
    for (int d = 0; d < 64; d++) s += wc[k * 64 + d] * v[d];   // wave-uniform broadcast
    dst[ki] = f2bf(s);
  }
}

// ---------------- transpose + cast: dst[n][k] = src[k][colOff + n] ----------------
__global__ __launch_bounds__(256) void transpose_cast(const float* __restrict__ src,
                                                      int srcStride, int colOff,
                                                      u16* __restrict__ dst, int Nt) {
  __shared__ float t[64][65];
  const int ntiles = Nt >> 6;
  const int n0 = (blockIdx.x % ntiles) * 64;
  const int k0 = (blockIdx.x / ntiles) * 64;
  for (int i = threadIdx.x; i < 4096; i += 256) {
    const int r = i >> 6, c = i & 63;
    t[r][c] = src[(size_t)(k0 + r) * srcStride + colOff + n0 + c];
  }
  __syncthreads();
  for (int i = threadIdx.x; i < 4096; i += 256) {
    const int r = i & 63, c = i >> 6;
    dst[(size_t)(n0 + c) * DIM + k0 + r] = f2bf(t[r][c]);
  }
}

// ---------------- 256x256 8-phase MFMA GEMM ----------------
// R7: even staging schedule — B(t+2)x2 @P3, A(t+2)x2 @P4, B(t+3)x2 @P7,
// A(t+3)x2 @P8; counted vmcnt(8) at P4/P8 (drains exactly the buffer needed
// next). Every load gets uniform 4-phase completion slack (was 1-3).
template <int EPI>
__global__ __launch_bounds__(512, 2) void gemm8p(const u16* __restrict__ A,
                                                 const u16* __restrict__ Bt,
                                                 void* __restrict__ Cout,
                                                 const float* __restrict__ bias,
                                                 int Nn, int K) {
  __shared__ __align__(16) u16 smem[2][2][2][128 * 64];  // [buf][A0/B1][half] = 128 KiB
  const int tilesN = Nn >> 8;
  const int cpx   = gridDim.x >> 3;
  const int xcd   = blockIdx.x & 7;
  const int local = blockIdx.x >> 3;
  const int bmPerX = cpx / tilesN;
  const int perG = 4 * tilesN;
  const int g = local / perG, rrm = local % perG;
  const int bm = xcd * bmPerX + g * 4 + rrm / tilesN;
  const int bn = rrm % tilesN;
  const int m0 = bm << 8, n0 = bn << 8;

  const int tid  = threadIdx.x;
  const int lane = tid & 63;
  const int w    = tid >> 6;
  const int wr = w >> 2, wcn = w & 3;
  const int lrow = lane & 15;
  const int hi   = lane >> 4;
  const int sx   = lrow & 7;

  const int srow  = tid >> 3;
  const int pslot = tid & 7;
  const int gk    = (pslot ^ (srow & 7)) << 3;
  const u16* aBase = A  + (size_t)m0 * K + gk;
  const u16* bBase = Bt + (size_t)n0 * K + gk;

#define STG(buf, op, half, kt, gb)                                             \
  { const u16* s0_ = (gb) + (size_t)((half) * 128 + srow) * K + (kt) * 64;     \
    char* d0_ = (char*)&smem[buf][op][half][0] + tid * 16;                     \
    gload_lds16(s0_, d0_);                                                     \
    gload_lds16(s0_ + (size_t)64 * K, d0_ + 8192); }

#define RDA(buf, dst, mbase)                                                   \
  _Pragma("unroll") for (int mi_ = 0; mi_ < 4; mi_++)                          \
  _Pragma("unroll") for (int kk_ = 0; kk_ < 2; kk_++) {                        \
    const int r_ = ((mbase) + mi_) * 16 + lrow;                                \
    dst[mi_][kk_] = *(const s16x8*)&smem[buf][0][wr]                           \
                        [r_ * 64 + ((kk_ * 4 + hi) ^ sx) * 8]; }

#define RDB(buf, dst, nbase)                                                   \
  _Pragma("unroll") for (int nj_ = 0; nj_ < 2; nj_++)                          \
  _Pragma("unroll") for (int kk_ = 0; kk_ < 2; kk_++) {                        \
    const int r_ = (wcn & 1) * 64 + ((nbase) + nj_) * 16 + lrow;               \
    dst[nj_][kk_] = *(const s16x8*)&smem[buf][1][wcn >> 1]                     \
                        [r_ * 64 + ((kk_ * 4 + hi) ^ sx) * 8]; }

#define MM(mbase, nbase, areg, breg)                                           \
  _Pragma("unroll") for (int mi_ = 0; mi_ < 4; mi_++)                          \
  _Pragma("unroll") for (int nj_ = 0; nj_ < 2; nj_++)                          \
  _Pragma("unroll") for (int kk_ = 0; kk_ < 2; kk_++)                          \
    acc[(mbase) + mi_][(nbase) + nj_] = __builtin_amdgcn_mfma_f32_16x16x32_bf16( \
        breg[nj_][kk_], areg[mi_][kk_], acc[(mbase) + mi_][(nbase) + nj_], 0, 0, 0);

#define WLG  asm volatile("s_waitcnt lgkmcnt(0)" ::: "memory")
#define WVM8 asm volatile("s_waitcnt vmcnt(8)" ::: "memory")
#define WVM0 asm volatile("s_waitcnt vmcnt(0)" ::: "memory")
#define BAR  __builtin_amdgcn_s_barrier()
#define PRIO1 __builtin_amdgcn_s_setprio(1)
#define PRIO0 __builtin_amdgcn_s_setprio(0)

  f32x4 acc[8][4] = {};
  const int NT  = K >> 6;
  const int NIT = NT >> 1;

  // prologue: buf0 <- tile0, buf1 <- tile1; drain buf0 (8 ops), keep 8 in flight
  STG(0, 0, 0, 0, aBase); STG(0, 0, 1, 0, aBase);
  STG(0, 1, 0, 0, bBase); STG(0, 1, 1, 0, bBase);
  STG(1, 0, 0, 1, aBase); STG(1, 0, 1, 1, aBase);
  STG(1, 1, 0, 1, bBase); STG(1, 1, 1, 1, bBase);
  WVM8; BAR;

  for (int it = 0; it < NIT; ++it) {
    const int tE = 2 * it + 2, tO = 2 * it + 3;
    const bool pf = (tE < NT);
    s16x8 a[4][2], bl[2][2], bh[2][2];
    // P1: Q(mlo,nlo) even tile
    RDA(0, a, 0); RDB(0, bl, 0);
    BAR; WLG;
    PRIO1; MM(0, 0, a, bl); PRIO0;
    BAR;
    // P2: Q(mlo,nhi)   (B buf0 fully read after this phase's WLG)
    RDB(0, bh, 2);
    BAR; WLG;
    PRIO1; MM(0, 2, a, bh); PRIO0;
    BAR;
    // P3: Q(mhi,nhi)   | stage b0.B both halves (tile tE)
    RDA(0, a, 4);
    if (pf) { STG(0, 1, 0, tE, bBase); STG(0, 1, 1, tE, bBase); }
    BAR; WLG;
    PRIO1; MM(4, 2, a, bh); PRIO0;
    BAR;
    // P4: Q(mhi,nlo)   | stage b0.A both halves; vmcnt(8) drains prev buf1
    if (pf) { STG(0, 0, 0, tE, aBase); STG(0, 0, 1, tE, aBase); }
    BAR;
    if (pf) { WVM8; } else { WVM0; }
    PRIO1; MM(4, 0, a, bl); PRIO0;
    BAR;
    // P5: Q(mlo,nlo) odd tile
    RDA(1, a, 0); RDB(1, bl, 0);
    BAR; WLG;
    PRIO1; MM(0, 0, a, bl); PRIO0;
    BAR;
    // P6: Q(mlo,nhi)
    RDB(1, bh, 2);
    BAR; WLG;
    PRIO1; MM(0, 2, a, bh); PRIO0;
    BAR;
    // P7: Q(mhi,nhi)   | stage b1.B both halves (tile tO)
    RDA(1, a, 4);
    if (pf) { STG(1, 1, 0, tO, bBase); STG(1, 1, 1, tO, bBase); }
    BAR; WLG;
    PRIO1; MM(4, 2, a, bh); PRIO0;
    BAR;
    // P8: Q(mhi,nlo)   | stage b1.A both halves; vmcnt(8) drains b0 (tile tE)
    if (pf) { STG(1, 0, 0, tO, aBase); STG(1, 0, 1, tO, aBase); }
    BAR;
    if (pf) { WVM8; } else { WVM0; }
    PRIO1; MM(4, 0, a, bl); PRIO0;
    BAR;
  }

  const int mrow = m0 + wr * 128 + lrow;
  const int nb0  = n0 + wcn * 64 + (hi << 2);
#pragma unroll
  for (int mi = 0; mi < 8; mi++) {
    const int row = mrow + mi * 16;
#pragma unroll
    for (int nj = 0; nj < 4; nj++) {
      const int nb = nb0 + nj * 16;
      float v0 = acc[mi][nj][0], v1 = acc[mi][nj][1];
      float v2 = acc[mi][nj][2], v3 = acc[mi][nj][3];
      if (EPI == 1) {
        if (nb < 2 * DIM) {
          const int bb = nb & 63;
          v0 += bias[bb];     v1 += bias[bb + 1];
          v2 += bias[bb + 2]; v3 += bias[bb + 3];
          v0 = v0 > 0.f ? v0 : 0.f;  v1 = v1 > 0.f ? v1 : 0.f;
          v2 = v2 > 0.f ? v2 : 0.f;  v3 = v3 > 0.f ? v3 : 0.f;
        }
        uint2 st;
        st.x = (uint32_t)f2bf(v0) | ((uint32_t)f2bf(v1) << 16);
        st.y = (uint32_t)f2bf(v2) | ((uint32_t)f2bf(v3) << 16);
        *(uint2*)((u16*)Cout + (size_t)row * Nn + nb) = st;
      } else {
        float4 st;
        st.x = v0 + bias[nb];     st.y = v1 + bias[nb + 1];
        st.z = v2 + bias[nb + 2]; st.w = v3 + bias[nb + 3];
        *(float4*)((float*)Cout + (size_t)row * Nn + nb) = st;
      }
    }
  }
#undef STG
#undef RDA
#undef RDB
#undef MM
#undef WLG
#undef WVM8
#undef WVM0
#undef BAR
#undef PRIO1
#undef PRIO0
}

// ---------------- kv partials via MFMA (unchanged from R6) ----------------
__global__ __launch_bounds__(256) void kv_ksum_mfma(const u16* __restrict__ qkv,
                                                    float* __restrict__ kvpart,
                                                    float* __restrict__ kspart) {
  const int bh = blockIdx.x >> 3;
  const int chunk = blockIdx.x & 7;
  const int b = bh >> 4, h = bh & 15;
  __shared__ u16 kT[64 * 64];   // [d][n swizzled]  8 KB
  __shared__ u16 vT[80 * 64];   // [e][n swizzled] 10 KB (rows 64..79 static)
  const int tid  = threadIdx.x;
  const int lane = tid & 63;
  const int w    = tid >> 6;
  const int lrow = lane & 15;
  const int hi   = lane >> 4;

  for (int i = tid; i < 16 * 64; i += 256) {
    const int r = 64 + (i >> 6), n = i & 63;
    vT[r * 64 + (((n >> 3) ^ (r & 7)) << 3) + (n & 7)] = (r == 64) ? (u16)0x3F80 : (u16)0;
  }

  f32x4 acc[5] = {};
  const u16* kbase = qkv + (size_t)(b * SEQ) * NQKV + DIM     + h * DHEAD;
  const u16* vbase = qkv + (size_t)(b * SEQ) * NQKV + 2 * DIM + h * DHEAD;

  for (int r0 = chunk * 512; r0 < chunk * 512 + 512; r0 += 64) {
    __syncthreads();
    for (int s = tid; s < 512; s += 256) {
      const int r  = s >> 3;
      const int c0 = (s & 7) << 3;
      const s16x8 k8 = *(const s16x8*)(kbase + (size_t)(r0 + r) * NQKV + c0);
      const s16x8 v8 = *(const s16x8*)(vbase + (size_t)(r0 + r) * NQKV + c0);
      const int slot = r >> 3, nb = r & 7;
#pragma unroll
      for (int q = 0; q < 8; q++) {
        const int d = c0 + q;
        const int off = d * 64 + ((slot ^ (d & 7)) << 3) + nb;
        kT[off] = (u16)k8[q];
        vT[off] = (u16)v8[q];
      }
    }
    __syncthreads();
#pragma unroll
    for (int kk = 0; kk < 2; kk++) {
      const int drow = w * 16 + lrow;
      const s16x8 kf = *(const s16x8*)&kT[drow * 64 + (((kk * 4 + hi) ^ (drow & 7)) << 3)];
#pragma unroll
      for (int et = 0; et < 5; et++) {
        const int erow = et * 16 + lrow;
        const s16x8 vf = *(const s16x8*)&vT[erow * 64 + (((kk * 4 + hi) ^ (erow & 7)) << 3)];
        acc[et] = __builtin_amdgcn_mfma_f32_16x16x32_bf16(vf, kf, acc[et], 0, 0, 0);
      }
    }
  }

  const int d = w * 16 + lrow;
  float* outp = kvpart + (size_t)blockIdx.x * 4096;
#pragma unroll
  for (int et = 0; et < 4; et++)
    *(f32x4*)&outp[d * 64 + et * 16 + hi * 4] = acc[et];
  if (hi == 0) kspart[(size_t)blockIdx.x * 64 + d] = acc[4][0];
}

// ---------------- deterministic partial reduction (unchanged) ----------------
__global__ __launch_bounds__(256) void reduce_kv(const float* __restrict__ kvpart,
                                                 const float* __restrict__ kspart,
                                                 float* __restrict__ kvbuf,
                                                 float* __restrict__ ksumb) {
  const int idx = blockIdx.x * 256 + threadIdx.x;
  if (idx < 64 * 4096) {
    const int bh = idx >> 12, i = idx & 4095;
    float s = 0.f;
#pragma unroll
    for (int c = 0; c < 8; c++) s += kvpart[(size_t)((bh << 3) + c) * 4096 + i];
    kvbuf[idx] = s;
  } else {
    const int idx2 = idx - 64 * 4096;
    if (idx2 < 4096) {
      const int bh = idx2 >> 6, i = idx2 & 63;
      float s = 0.f;
#pragma unroll
      for (int c = 0; c < 8; c++) s += kspart[((bh << 3) + c) * 64 + i];
      ksumb[idx2] = s;
    }
  }
}

// ---------------- attn out via MFMA (unchanged from R5) ----------------
__global__ __launch_bounds__(256) void attn_mfma(const u16* __restrict__ qkv,
                                                 const float* __restrict__ kvbuf,
                                                 const float* __restrict__ ksumb,
                                                 u16* __restrict__ attn) {
  const int bh = blockIdx.x >> 4;        // 0..63
  const int mc = blockIdx.x & 15;        // 256-row chunk
  const int b = bh >> 4, h = bh & 15;
  __shared__ u16 BT[2][80][64];          // [hi/lo][e-row][swizzled d], 20.5 KB
  __shared__ float nrm[256];
  const int tid  = threadIdx.x;
  const int lane = tid & 63;
  const int w    = tid >> 6;
  const int lrow = lane & 15;
  const int hi   = lane >> 4;

#pragma unroll
  for (int s = 0; s < 20; s++) {
    const int idx = tid + 256 * s;       // 0..5119
    const int e = idx >> 6, d = idx & 63;
    float v;
    if (e < 64)       v = kvbuf[(size_t)bh * 4096 + d * 64 + e];
    else if (e == 64) v = ksumb[bh * 64 + d];
    else              v = 0.f;
    const u16 vh = f2bf(v);
    const u16 vl = f2bf(v - bf2f(vh));
    const int off = e * 64 + (((d >> 3) ^ (e & 7)) << 3) + (d & 7);
    BT[0][0][off] = vh;
    BT[1][0][off] = vl;
  }

  const int rloc = w * 64 + lrow;        // + mi*16
  const u16* qbase = qkv + (size_t)(b * SEQ + mc * 256 + rloc) * NQKV + h * DHEAD + hi * 8;
  s16x8 af[4][2];
#pragma unroll
  for (int mi = 0; mi < 4; mi++)
#pragma unroll
    for (int kk = 0; kk < 2; kk++)
      af[mi][kk] = *(const s16x8*)(qbase + (size_t)(mi * 16) * NQKV + kk * 32);

  __syncthreads();

  f32x4 acc[4][5] = {};
#pragma unroll
  for (int wv = 0; wv < 2; wv++) {
#pragma unroll
    for (int jb = 0; jb < 5; jb++) {
      const int erow = jb * 16 + lrow;
      const int sx = erow & 7;
      s16x8 bq0 = *(const s16x8*)&BT[wv][erow][((0 * 4 + hi) ^ sx) << 3];
      s16x8 bq1 = *(const s16x8*)&BT[wv][erow][((1 * 4 + hi) ^ sx) << 3];
#pragma unroll
      for (int mi = 0; mi < 4; mi++) {
        acc[mi][jb] = __builtin_amdgcn_mfma_f32_16x16x32_bf16(bq0, af[mi][0], acc[mi][jb], 0, 0, 0);
        acc[mi][jb] = __builtin_amdgcn_mfma_f32_16x16x32_bf16(bq1, af[mi][1], acc[mi][jb], 0, 0, 0);
      }
    }
  }

  if (hi == 0) {
#pragma unroll
    for (int mi = 0; mi < 4; mi++) nrm[rloc + mi * 16] = acc[mi][4][0] + 1e-6f;
  }
  __syncthreads();

  u16* obase = attn + (size_t)(b * SEQ + mc * 256 + rloc) * DIM + h * DHEAD + hi * 4;
#pragma unroll
  for (int mi = 0; mi < 4; mi++) {
    const float sc = 1.f / nrm[rloc + mi * 16];
#pragma unroll
    for (int jb = 0; jb < 4; jb++) {
      uint2 st;
      st.x = (uint32_t)f2bf(acc[mi][jb][0] * sc) | ((uint32_t)f2bf(acc[mi][jb][1] * sc) << 16);
      st.y = (uint32_t)f2bf(acc[mi][jb][2] * sc) | ((uint32_t)f2bf(acc[mi][jb][3] * sc) << 16);
      *(uint2*)(obase + (size_t)(mi * 16) * DIM + jb * 16) = st;
    }
  }
}

extern "C" void kernel_launch(void* const* d_in, const int* in_sizes, int n_in,
                              void* d_out, int out_size, void* d_ws, size_t ws_size,
                              hipStream_t stream) {
  (void)in_sizes; (void)n_in; (void)out_size; (void)ws_size;
  const float* x     = (const float*)d_in[0];
  const float* Wqkv  = (const float*)d_in[1];
  const float* Wf    = (const float*)d_in[2];
  const float* bfv   = (const float*)d_in[3];
  const float* Wout  = (const float*)d_in[4];
  const float* bout  = (const float*)d_in[5];
  float* out = (float*)d_out;
  char* ws = (char*)d_ws;

  u16*   wqkvT = (u16*)(ws + 0);              // 3072*1024 bf16   = 6,291,456 B
  u16*   woutT = (u16*)(ws + 6291456);        // 1024*1024 bf16   = 2,097,152 B
  u16*   xb    = (u16*)(ws + 8388608);        // 16384*1024 bf16  = 33,554,432 B
  u16*   qkvb  = (u16*)(ws + 41943040);       // 16384*3072 bf16  = 100,663,296 B
  u16*   attn  = (u16*)(ws + 142606336);      // 16384*1024 bf16  = 33,554,432 B
  float* kvp   = (float*)(ws + 176160768);    // 512*4096 f32     = 8,388,608 B
  float* ksp   = (float*)(ws + 184549376);    // 512*64 f32       = 131,072 B
  float* kvbuf = (float*)(ws + 184680448);    // 64*4096 f32      = 1,048,576 B
  float* ksumb = (float*)(ws + 185729024);    // 64*64 f32        = 16,384 B

  cast_f32_bf16<<<2048, 256, 0, stream>>>(x, xb, MROWS * DIM);
  fold_qk<<<256, 256, 0, stream>>>(Wqkv, Wf, wqkvT);
  transpose_cast<<<256, 256, 0, stream>>>(Wqkv, NQKV, 2 * DIM, wqkvT + (size_t)2 * DIM * DIM, DIM);
  transpose_cast<<<256, 256, 0, stream>>>(Wout, DIM, 0, woutT, DIM);
  gemm8p<1><<<(MROWS / 256) * (NQKV / 256), 512, 0, stream>>>(xb, wqkvT, qkvb, bfv,
                                                              NQKV, DIM);
  kv_ksum_mfma<<<64 * 8, 256, 0, stream>>>(qkvb, kvp, ksp);
  reduce_kv<<<(64 * 4096 + 64 * 64 + 255) / 256, 256, 0, stream>>>(kvp, ksp, kvbuf, ksumb);
  attn_mfma<<<64 * 16, 256, 0, stream>>>(qkvb, kvbuf, ksumb, attn);
  gemm8p<2><<<(MROWS / 256) * (DIM / 256), 512, 0, stream>>>(attn, woutT, out, bout,
                                                             DIM, DIM);
}